// Round 5
// baseline (741.386 us; speedup 1.0000x reference)
//
#include <hip/hip_runtime.h>
#include <math.h>

#define S     64
#define NSUB  1024
#define ESUB  16384
#define NG    65536
#define EG    1048576
#define NH    128
#define KSEL  512
#define BCAP  20480   // per-bucket ebin capacity; bucket ~ Binom(1M,1/64): mean 16384, sd 127

// ---- fused per-subgraph CSR: LDS hist + LDS scan + LDS-cursor fill (one block/subgraph)
// blocks 64..127 handle the folded countR for the node->row inverse CSR.
__global__ __launch_bounds__(1024) void k_csr_sub(const int* __restrict__ sei,
        const int* __restrict__ sorig, int* __restrict__ rowptr, int* __restrict__ col,
        float* __restrict__ dinv, int* __restrict__ cntR) {
    int b = blockIdx.x, t = threadIdx.x;
    if (b >= 64) {                                   // folded countR (NG entries)
        int r = (b - 64) * 1024 + t;
        atomicAdd(&cntR[sorig[r]], 1);
        return;
    }
    __shared__ int sh[1024];
    __shared__ int curL[1024];
    int s = b;
    curL[t] = 0;
    __syncthreads();
    const int* dstp = sei + s * 2 * ESUB + ESUB;
    #pragma unroll
    for (int k = 0; k < 16; k++) atomicAdd(&curL[dstp[k * 1024 + t]], 1);
    __syncthreads();
    int v = curL[t];
    sh[t] = v;
    __syncthreads();
    for (int off = 1; off < 1024; off <<= 1) {
        int add = (t >= off) ? sh[t - off] : 0;
        __syncthreads();
        sh[t] += add;
        __syncthreads();
    }
    int incl = sh[t];
    int excl = incl - v;
    rowptr[s * (NSUB + 1) + t] = excl;
    dinv[s * NSUB + t] = rsqrtf((float)(v + 1));     // deg = indeg + 1 (self loop)
    if (t == 1023) rowptr[s * (NSUB + 1) + NSUB] = incl;
    curL[t] = s * ESUB + excl;                       // absolute cursor
    __syncthreads();
    const int* srcp = sei + s * 2 * ESUB;
    #pragma unroll
    for (int k = 0; k < 16; k++) {
        int e = k * 1024 + t;
        int src = srcp[e];
        int dst = dstp[e];
        int p = atomicAdd(&curL[dst], 1);
        col[p] = src;
    }
}

// -------- matmul 128x128 tile, 8x8 acc/thread: Y[M,128] = X[M,KDIM] @ W[KDIM,128] ------
// k ascends exactly as the old 64x64 kernel -> bitwise-identical accumulation order.
template<int KDIM>
__global__ __launch_bounds__(256) void k_matmul128(const float* __restrict__ X,
        const float* __restrict__ W, float* __restrict__ Y) {
    __shared__ float As[16][136];   // [k][row], stride 136 (544B, 16B-aligned)
    __shared__ float Bs[16][136];   // [k][col]
    int t = threadIdx.x;
    int row0 = blockIdx.x * 128;
    int tr = t >> 4, tc = t & 15;
    float acc[8][8] = {};
    for (int k0 = 0; k0 < KDIM; k0 += 16) {
        {   // stage A: 128 rows x 16 k (2 threads/row, 8 floats each)
            int r = t >> 1, half = t & 1;
            const float* xp = &X[(size_t)(row0 + r) * KDIM + k0 + half * 8];
            float4 v0 = *(const float4*)xp;
            float4 v1 = *(const float4*)(xp + 4);
            int kb = half * 8;
            As[kb + 0][r] = v0.x; As[kb + 1][r] = v0.y; As[kb + 2][r] = v0.z; As[kb + 3][r] = v0.w;
            As[kb + 4][r] = v1.x; As[kb + 5][r] = v1.y; As[kb + 6][r] = v1.z; As[kb + 7][r] = v1.w;
        }
        {   // stage B: 16 k x 128 cols (2 float4 per thread)
            int k = t >> 4, c = (t & 15) * 4;
            *(float4*)&Bs[k][c]      = *(const float4*)&W[(size_t)(k0 + k) * 128 + c];
            *(float4*)&Bs[k][c + 64] = *(const float4*)&W[(size_t)(k0 + k) * 128 + c + 64];
        }
        __syncthreads();
        #pragma unroll
        for (int k = 0; k < 16; k++) {
            float a[8], b[8];
            *(float4*)&a[0] = *(const float4*)&As[k][tr * 8];
            *(float4*)&a[4] = *(const float4*)&As[k][tr * 8 + 4];
            *(float4*)&b[0] = *(const float4*)&Bs[k][tc * 8];
            *(float4*)&b[4] = *(const float4*)&Bs[k][tc * 8 + 4];
            #pragma unroll
            for (int i = 0; i < 8; i++)
                #pragma unroll
                for (int j = 0; j < 8; j++)
                    acc[i][j] += a[i] * b[j];
        }
        __syncthreads();
    }
    #pragma unroll
    for (int i = 0; i < 8; i++) {
        float4 v0 = { acc[i][0], acc[i][1], acc[i][2], acc[i][3] };
        float4 v1 = { acc[i][4], acc[i][5], acc[i][6], acc[i][7] };
        float* yp = &Y[(size_t)(row0 + tr * 8 + i) * 128 + tc * 8];
        *(float4*)yp = v0;
        *(float4*)(yp + 4) = v1;
    }
}

// ------- GCN aggregate (128 feats) + self + bias + relu; float4 + XCD swizzle --------
template<bool SCORE>
__global__ __launch_bounds__(256) void k_agg128(const float4* __restrict__ h,
        const float* __restrict__ dinv, const int* __restrict__ rowptr,
        const int* __restrict__ col, const float* __restrict__ bias,
        const float* __restrict__ Wp, float4* __restrict__ out,
        float* __restrict__ scoreh) {
    int b = blockIdx.x;
    int s = b & 63;                      // subgraph -> fixed XCD (b%8 == s%8)
    int chunk = b >> 6;
    int t = threadIdx.x;
    int nl = chunk * 8 + (t >> 5);
    int f4 = t & 31;
    const int* rp = rowptr + s * (NSUB + 1);
    int st = rp[nl], en = rp[nl + 1];
    const int* cl = col + s * ESUB;
    const float* dv = dinv + s * NSUB;
    float4 acc = {0.f, 0.f, 0.f, 0.f};
    for (int p = st; p < en; p++) {
        int src = cl[p];
        float d = dv[src];
        float4 hv = h[((size_t)(s * NSUB + src)) * 32 + f4];
        acc.x += hv.x * d; acc.y += hv.y * d; acc.z += hv.z * d; acc.w += hv.w * d;
    }
    size_t node = (size_t)s * NSUB + nl;
    float dn = dv[nl];
    float dn2 = dn * dn;
    float4 hs = h[node * 32 + f4];
    float4 bb = ((const float4*)bias)[f4];
    float4 r;
    r.x = fmaxf(acc.x * dn + hs.x * dn2 + bb.x, 0.f);
    r.y = fmaxf(acc.y * dn + hs.y * dn2 + bb.y, 0.f);
    r.z = fmaxf(acc.z * dn + hs.z * dn2 + bb.z, 0.f);
    r.w = fmaxf(acc.w * dn + hs.w * dn2 + bb.w, 0.f);
    out[node * 32 + f4] = r;
    if (SCORE) {
        float4 wp = ((const float4*)Wp)[f4];
        float p = r.x * wp.x + r.y * wp.y + r.z * wp.z + r.w * wp.w;
        #pragma unroll
        for (int o = 16; o > 0; o >>= 1) p += __shfl_xor(p, o, 32);
        if (f4 == 0) scoreh[node] = p;
    }
}

__global__ void k_score_agg(const float* __restrict__ sh, const float* __restrict__ dinv,
                            const int* __restrict__ rowptr, const int* __restrict__ col,
                            const float* __restrict__ bp, float* __restrict__ score) {
    int n = blockIdx.x * 256 + threadIdx.x;
    int s = n >> 10, nl = n & (NSUB - 1);
    const int* rp = rowptr + s * (NSUB + 1);
    const int* cl = col + s * ESUB;
    const float* dv = dinv + s * NSUB;
    int st = rp[nl], en = rp[nl + 1];
    float acc = 0.f;
    for (int p = st; p < en; p++) {
        int src = cl[p];
        acc += sh[s * NSUB + src] * dv[src];
    }
    float dn = dv[nl];
    score[n] = acc * dn + sh[n] * dn * dn + bp[0];
}

// ---------------- per-subgraph top-K (bitonic; set-invariant downstream) -----
__global__ __launch_bounds__(512) void k_topk(const float* __restrict__ score,
        int* __restrict__ perm, float* __restrict__ gate, int* __restrict__ posmap) {
    __shared__ float sv[1024];
    __shared__ int   si[1024];
    int s = blockIdx.x, t = threadIdx.x;
    for (int i = t; i < 1024; i += 512) {
        sv[i] = score[s * NSUB + i];
        si[i] = i;
        posmap[s * NSUB + i] = -1;
    }
    __syncthreads();
    for (int k = 2; k <= 1024; k <<= 1) {
        for (int j = k >> 1; j > 0; j >>= 1) {
            for (int b = t; b < 1024; b += 512) {
                int ixj = b ^ j;
                if (ixj > b) {
                    bool desc = ((b & k) == 0);
                    bool sw = desc ? (sv[b] < sv[ixj]) : (sv[b] > sv[ixj]);
                    if (sw) {
                        float tv = sv[b]; sv[b] = sv[ixj]; sv[ixj] = tv;
                        int ti = si[b]; si[b] = si[ixj]; si[ixj] = ti;
                    }
                }
            }
            __syncthreads();
        }
    }
    if (t < KSEL) {
        perm[s * KSEL + t] = si[t];
        gate[s * KSEL + t] = tanhf(sv[t]);
        posmap[s * NSUB + si[t]] = t;
    }
}

// fused deg2 + xpool
__global__ __launch_bounds__(256) void k_pool(const float4* __restrict__ x1,
        const int* __restrict__ perm, const float* __restrict__ gate,
        const int* __restrict__ posmap, const int* __restrict__ rowptr,
        const int* __restrict__ col, float* __restrict__ dinv2,
        float4* __restrict__ xpool) {
    int t = threadIdx.x;
    int i = blockIdx.x * 8 + (t >> 5);
    int lane = t & 31;
    int s = i >> 9;
    int n = perm[i];
    const int* rp = rowptr + s * (NSUB + 1);
    const int* cl = col + s * ESUB;
    int st = rp[n], en = rp[n + 1];
    int c = 0;
    for (int p = st + lane; p < en; p += 32) c += (posmap[s * NSUB + cl[p]] >= 0) ? 1 : 0;
    #pragma unroll
    for (int o = 16; o > 0; o >>= 1) c += __shfl_xor(c, o, 32);
    if (lane == 0) dinv2[i] = rsqrtf((float)(c + 1));
    float g = gate[i];
    float4 v = x1[((size_t)(s * NSUB + n)) * 32 + lane];
    v.x *= g; v.y *= g; v.z *= g; v.w *= g;
    xpool[(size_t)i * 32 + lane] = v;
}

// max/mean over 512 rows -> [256] per subgraph
__global__ __launch_bounds__(1024) void k_emb(const float* __restrict__ X,
        float* __restrict__ out) {
    __shared__ float red[4][256];
    int s = blockIdx.x, t = threadIdx.x;
    int sl = t >> 8, f = t & 255;
    const float* base = X + (size_t)s * KSEL * NH;
    float r;
    if (f < NH) {
        r = -INFINITY;
        for (int i = sl * 128; i < sl * 128 + 128; i++) r = fmaxf(r, base[i * NH + f]);
    } else {
        r = 0.f;
        for (int i = sl * 128; i < sl * 128 + 128; i++) r += base[i * NH + (f - NH)];
    }
    red[sl][f] = r;
    __syncthreads();
    if (sl == 0) {
        float a = red[0][f], b = red[1][f], c = red[2][f], d = red[3][f];
        float v = (f < NH) ? fmaxf(fmaxf(a, b), fmaxf(c, d)) : (a + b + c + d) * (1.f / KSEL);
        out[s * 256 + f] = v;
    }
}

// emb pass 2 + degenerate attention + AW = att @ Wf[128:384]
__global__ __launch_bounds__(1024) void k_emb_attn(const float* __restrict__ X,
        const float* __restrict__ subemb, const float* __restrict__ Wqkv,
        const float* __restrict__ bqkv, const float* __restrict__ Wo,
        const float* __restrict__ bo, const float* __restrict__ Wf,
        float* __restrict__ att, float* __restrict__ AW) {
    __shared__ float red[4][256];
    __shared__ float se[256], t1[256], av[256];
    int s = blockIdx.x, t = threadIdx.x;
    int sl = t >> 8, f = t & 255;
    const float* base = X + (size_t)s * KSEL * NH;
    float r;
    if (f < NH) {
        r = -INFINITY;
        for (int i = sl * 128; i < sl * 128 + 128; i++) r = fmaxf(r, base[i * NH + f]);
    } else {
        r = 0.f;
        for (int i = sl * 128; i < sl * 128 + 128; i++) r += base[i * NH + (f - NH)];
    }
    red[sl][f] = r;
    __syncthreads();
    if (sl == 0) {
        float a = red[0][f], b = red[1][f], c = red[2][f], d = red[3][f];
        float v = (f < NH) ? fmaxf(fmaxf(a, b), fmaxf(c, d)) : (a + b + c + d) * (1.f / KSEL);
        se[f] = subemb[s * 256 + f] + v;
    }
    __syncthreads();
    if (sl == 0) {
        float acc = bqkv[512 + f];
        for (int k = 0; k < 256; k++) acc += se[k] * Wqkv[(size_t)k * 768 + 512 + f];
        t1[f] = acc;
    }
    __syncthreads();
    if (sl == 0) {
        float a2 = bo[f];
        for (int k = 0; k < 256; k++) a2 += t1[k] * Wo[(size_t)k * 256 + f];
        att[s * 256 + f] = a2;
        av[f] = a2;
    }
    __syncthreads();
    if (sl == 0 && f < 64) {
        float acc = 0.f;
        for (int k = 0; k < 256; k++) acc += av[k] * Wf[(size_t)(NH + k) * 64 + f];
        AW[s * 64 + f] = acc;
    }
}

// pooled GCN aggregate
__global__ __launch_bounds__(256) void k_agg_pool(const float4* __restrict__ hp,
        const float* __restrict__ dinv2, const int* __restrict__ perm,
        const int* __restrict__ posmap, const int* __restrict__ rowptr,
        const int* __restrict__ col, const float* __restrict__ bsc,
        float4* __restrict__ xsub) {
    int b = blockIdx.x;
    int s = b & 63;
    int chunk = b >> 6;
    int t = threadIdx.x;
    int il = chunk * 8 + (t >> 5);
    int f4 = t & 31;
    int i = s * KSEL + il;
    int n = perm[i];
    const int* rp = rowptr + s * (NSUB + 1);
    const int* cl = col + s * ESUB;
    int st = rp[n], en = rp[n + 1];
    float4 acc = {0.f, 0.f, 0.f, 0.f};
    for (int p = st; p < en; p++) {
        int j = posmap[s * NSUB + cl[p]];
        if (j >= 0) {
            float d = dinv2[s * KSEL + j];
            float4 hv = hp[((size_t)(s * KSEL + j)) * 32 + f4];
            acc.x += hv.x * d; acc.y += hv.y * d; acc.z += hv.z * d; acc.w += hv.w * d;
        }
    }
    float dn = dinv2[i];
    float dn2 = dn * dn;
    float4 hs = hp[(size_t)i * 32 + f4];
    float4 bb = ((const float4*)bsc)[f4];
    float4 r;
    r.x = fmaxf(acc.x * dn + hs.x * dn2 + bb.x, 0.f);
    r.y = fmaxf(acc.y * dn + hs.y * dn2 + bb.y, 0.f);
    r.z = fmaxf(acc.z * dn + hs.z * dn2 + bb.z, 0.f);
    r.w = fmaxf(acc.w * dn + hs.w * dn2 + bb.w, 0.f);
    xsub[(size_t)i * 32 + f4] = r;
}

// ---- fused scanR (p1+p3): per-block prefix self-computed; also inits bcur -----
__global__ __launch_bounds__(1024) void k_scanR(const int* __restrict__ cnt,
        int* __restrict__ rowptr, int* __restrict__ cur, int* __restrict__ bcur) {
    __shared__ int sh[1024];
    __shared__ int wsum[16];
    __shared__ int sboff;
    int b = blockIdx.x, t = threadIdx.x;
    if (b == 0 && t < 64) bcur[t] = t * BCAP;        // init for later binN reservations
    int pre = 0;
    for (int i = t; i < b * 1024; i += 1024) pre += cnt[i];
    #pragma unroll
    for (int o = 32; o > 0; o >>= 1) pre += __shfl_xor(pre, o, 64);
    if ((t & 63) == 0) wsum[t >> 6] = pre;
    __syncthreads();
    if (t == 0) {
        int r = 0;
        #pragma unroll
        for (int i = 0; i < 16; i++) r += wsum[i];
        sboff = r;
    }
    int v = cnt[b * 1024 + t];
    sh[t] = v;
    __syncthreads();
    for (int off = 1; off < 1024; off <<= 1) {
        int add = (t >= off) ? sh[t - off] : 0;
        __syncthreads();
        sh[t] += add;
        __syncthreads();
    }
    int base = sboff;
    int r = base + sh[t] - v;
    int idx = b * 1024 + t;
    rowptr[idx] = r;
    cur[idx] = r;
    if (b == 63 && t == 1023) rowptr[NG] = base + sh[t];   // = NG
}

// ---- fused: blocks [0,256) fillR; blocks [256,384) binN (independent) --------
__global__ __launch_bounds__(256) void k_fbN(const int* __restrict__ orig,
        int* __restrict__ cur, int* __restrict__ rowlist,
        const int* __restrict__ gei, int* __restrict__ bcur, int* __restrict__ ebin) {
    int t = threadIdx.x;
    if (blockIdx.x < 256) {                          // fillR
        int r = blockIdx.x * 256 + t;
        int p = atomicAdd(&cur[orig[r]], 1);
        rowlist[p] = r;
        return;
    }
    // binN: fixed-capacity bucket binning of global edges by dst>>10
    __shared__ int lh[64];
    __shared__ int lbase[64];
    if (t < 64) lh[t] = 0;
    __syncthreads();
    int e0 = (blockIdx.x - 256) * 8192;
    #pragma unroll 8
    for (int k = 0; k < 32; k++) {
        int d = gei[EG + e0 + k * 256 + t];
        atomicAdd(&lh[d >> 10], 1);
    }
    __syncthreads();
    if (t < 64) {
        lbase[t] = atomicAdd(&bcur[t], lh[t]);
        lh[t] = 0;
    }
    __syncthreads();
    #pragma unroll 4
    for (int k = 0; k < 32; k++) {
        int idx = e0 + k * 256 + t;
        int d = gei[EG + idx];
        int src = gei[idx];
        int bb = d >> 10;
        int pos = lbase[bb] + atomicAdd(&lh[bb], 1);
        ebin[pos] = src | ((d & 1023) << 16);
    }
}

// ---- fused: blocks [0,NG/4) gather gemb; blocks [NG/4, NG/4+NG/64) X2W matmul ----
__global__ __launch_bounds__(384) void k_gather_x2w(const float4* __restrict__ x2,
        const float4* __restrict__ att, const int* __restrict__ rowptrR,
        const int* __restrict__ rowlist, float4* __restrict__ gemb,
        const float* __restrict__ X, const float* __restrict__ W,
        float* __restrict__ Y) {
    int t = threadIdx.x;
    if (blockIdx.x < NG / 4) {                       // gather (384 threads)
        int g = blockIdx.x * 4 + (t / 96);
        int lane = t % 96;
        int st = rowptrR[g], en = rowptrR[g + 1];
        float4 acc = {0.f, 0.f, 0.f, 0.f};
        for (int p = st; p < en; p++) {
            int row = rowlist[p];
            float4 v = (lane < 32) ? x2[(size_t)row * 32 + lane]
                                   : att[(size_t)(row >> 10) * 64 + (lane - 32)];
            acc.x += v.x; acc.y += v.y; acc.z += v.z; acc.w += v.w;
        }
        gemb[(size_t)g * 96 + lane] = acc;
        return;
    }
    // 64x64 matmul, K=128 NCOL=64 (X2W = x2 @ Wf[0:128]); 256 active of 384
    __shared__ float As[16][72];
    __shared__ float Bs[16][72];
    int row0 = (blockIdx.x - NG / 4) * 64;
    int tr = t >> 4, tc = t & 15;
    float acc[4][4] = {};
    for (int k0 = 0; k0 < 128; k0 += 16) {
        if (t < 256) {
            {
                int r = t >> 2, kq = t & 3;
                float4 v = *(const float4*)&X[(size_t)(row0 + r) * 128 + k0 + kq * 4];
                As[kq * 4 + 0][r] = v.x; As[kq * 4 + 1][r] = v.y;
                As[kq * 4 + 2][r] = v.z; As[kq * 4 + 3][r] = v.w;
            }
            {
                int k = t >> 4, cq = t & 15;
                float4 v = *(const float4*)&W[(size_t)(k0 + k) * 64 + cq * 4];
                *(float4*)&Bs[k][cq * 4] = v;
            }
        }
        __syncthreads();
        if (t < 256) {
            #pragma unroll
            for (int k = 0; k < 16; k++) {
                float a0 = As[k][tr * 4 + 0], a1 = As[k][tr * 4 + 1];
                float a2 = As[k][tr * 4 + 2], a3 = As[k][tr * 4 + 3];
                float b0 = Bs[k][tc * 4 + 0], b1 = Bs[k][tc * 4 + 1];
                float b2 = Bs[k][tc * 4 + 2], b3 = Bs[k][tc * 4 + 3];
                acc[0][0] += a0 * b0; acc[0][1] += a0 * b1; acc[0][2] += a0 * b2; acc[0][3] += a0 * b3;
                acc[1][0] += a1 * b0; acc[1][1] += a1 * b1; acc[1][2] += a1 * b2; acc[1][3] += a1 * b3;
                acc[2][0] += a2 * b0; acc[2][1] += a2 * b1; acc[2][2] += a2 * b2; acc[2][3] += a2 * b3;
                acc[3][0] += a3 * b0; acc[3][1] += a3 * b1; acc[3][2] += a3 * b2; acc[3][3] += a3 * b3;
            }
        }
        __syncthreads();
    }
    if (t < 256) {
        #pragma unroll
        for (int i = 0; i < 4; i++) {
            float4 v = { acc[i][0], acc[i][1], acc[i][2], acc[i][3] };
            *(float4*)&Y[(size_t)(row0 + tr * 4 + i) * 64 + tc * 4] = v;
        }
    }
}

// ---- fused: blocks [0,1024) gatherH (64 nodes/blk); blocks [1024,1088) fillB3 ----
__global__ __launch_bounds__(1024) void k_gatherH_fB3(const float4* __restrict__ X2W,
        const float4* __restrict__ AW, const int* __restrict__ rowptrR,
        const int* __restrict__ rowlist, float4* __restrict__ hf,
        const int* __restrict__ ebin, const int* __restrict__ bcur,
        int* __restrict__ rowptrN, float* __restrict__ dinvN, int* __restrict__ colN) {
    int t = threadIdx.x;
    if (blockIdx.x < 1024) {                         // gatherH: hf[g] = sum(X2W[row]+AW[sub])
        int g = blockIdx.x * 64 + (t >> 4);
        int f4 = t & 15;
        int st = rowptrR[g], en = rowptrR[g + 1];
        float4 acc = {0.f, 0.f, 0.f, 0.f};
        for (int p = st; p < en; p++) {
            int row = rowlist[p];
            float4 a = X2W[(size_t)row * 16 + f4];
            float4 b = AW[(size_t)(row >> 10) * 16 + f4];
            acc.x += a.x + b.x; acc.y += a.y + b.y; acc.z += a.z + b.z; acc.w += a.w + b.w;
        }
        hf[(size_t)g * 16 + f4] = acc;
        return;
    }
    // fillB3: one block per bucket -> LDS hist/scan -> rowptrN/dinvN + LDS-cursor fill
    __shared__ int sh[1024];
    __shared__ int curL[1024];
    __shared__ int sbase;
    int b = blockIdx.x - 1024;
    if (t == 0) {
        int run = 0;
        for (int i = 0; i < b; i++) run += bcur[i] - i * BCAP;
        sbase = run;
    }
    curL[t] = 0;
    __syncthreads();
    int st = b * BCAP, en = bcur[b];
    for (int i = st + t; i < en; i += 1024) atomicAdd(&curL[ebin[i] >> 16], 1);
    __syncthreads();
    int v = curL[t];
    sh[t] = v;
    __syncthreads();
    for (int off = 1; off < 1024; off <<= 1) {
        int add = (t >= off) ? sh[t - off] : 0;
        __syncthreads();
        sh[t] += add;
        __syncthreads();
    }
    int incl = sh[t];
    int excl = incl - v;
    int base = sbase;
    rowptrN[(b << 10) + t] = base + excl;
    dinvN[(b << 10) + t] = rsqrtf((float)(v + 1));
    if (b == 63 && t == 1023) rowptrN[NG] = base + incl;   // = EG
    curL[t] = base + excl;
    __syncthreads();
    for (int i = st + t; i < en; i += 1024) {
        int packed = ebin[i];
        int p = atomicAdd(&curL[packed >> 16], 1);
        colN[p] = packed & 0xFFFF;
    }
}

// final GCN aggregate + bias + log_softmax (64 classes = 16 float4 lanes)
__global__ __launch_bounds__(256) void k_final(const float4* __restrict__ hf,
        const float* __restrict__ dinvN, const int* __restrict__ rowptr,
        const int* __restrict__ col, const float* __restrict__ bfb,
        float4* __restrict__ out) {
    int t = threadIdx.x;
    int n = blockIdx.x * 16 + (t >> 4);
    int f4 = t & 15;
    int st = rowptr[n], en = rowptr[n + 1];
    float4 acc = {0.f, 0.f, 0.f, 0.f};
    for (int p = st; p < en; p++) {
        int src = col[p];
        float d = dinvN[src];
        float4 hv = hf[(size_t)src * 16 + f4];
        acc.x += hv.x * d; acc.y += hv.y * d; acc.z += hv.z * d; acc.w += hv.w * d;
    }
    float dn = dinvN[n];
    float dn2 = dn * dn;
    float4 hs = hf[(size_t)n * 16 + f4];
    float4 bb = ((const float4*)bfb)[f4];
    float4 x;
    x.x = acc.x * dn + hs.x * dn2 + bb.x;
    x.y = acc.y * dn + hs.y * dn2 + bb.y;
    x.z = acc.z * dn + hs.z * dn2 + bb.z;
    x.w = acc.w * dn + hs.w * dn2 + bb.w;
    float m = fmaxf(fmaxf(x.x, x.y), fmaxf(x.z, x.w));
    for (int o = 1; o < 16; o <<= 1) m = fmaxf(m, __shfl_xor(m, o, 64));
    float ssum = expf(x.x - m) + expf(x.y - m) + expf(x.z - m) + expf(x.w - m);
    for (int o = 1; o < 16; o <<= 1) ssum += __shfl_xor(ssum, o, 64);
    float lz = m + logf(ssum);
    float4 r = { x.x - lz, x.y - lz, x.z - lz, x.w - lz };
    out[(size_t)n * 16 + f4] = r;
}

// ---------------- host ----------------
extern "C" void kernel_launch(void* const* d_in, const int* in_sizes, int n_in,
                              void* d_out, int out_size, void* d_ws, size_t ws_size,
                              hipStream_t stream) {
    const float* sub_x = (const float*)d_in[0];
    const int*   sei   = (const int*)d_in[1];
    const int*   sorig = (const int*)d_in[2];
    const int*   gei   = (const int*)d_in[3];
    const float *W1 = (const float*)d_in[4],  *b1  = (const float*)d_in[5];
    const float *W2 = (const float*)d_in[6],  *b2  = (const float*)d_in[7];
    const float *Wp = (const float*)d_in[8],  *bp  = (const float*)d_in[9];
    const float *Wsc = (const float*)d_in[10], *bsc = (const float*)d_in[11];
    const float *Wqkv = (const float*)d_in[12], *bqkv = (const float*)d_in[13];
    const float *Wo = (const float*)d_in[14], *bo  = (const float*)d_in[15];
    const float *Wf = (const float*)d_in[16], *bfb = (const float*)d_in[17];

    float* out0 = (float*)d_out;                      // log-softmax [NG,64]
    float* gemb = (float*)d_out + (size_t)NG * 64;    // global_emb [NG,384] in-place

    char* w = (char*)d_ws;
    size_t off = 0;
    auto alloc = [&](size_t nbytes) -> void* {
        off = (off + 255) & ~(size_t)255;
        void* p = w + off;
        off += nbytes;
        return p;
    };
    int*   bcur    = (int*)alloc(64 * 4);
    float* AW      = (float*)alloc((size_t)S * 64 * 4);
    float* dinv    = (float*)alloc((size_t)NG * 4);        // subgraph dinv; later dinvN
    float* scoreh  = (float*)alloc((size_t)NG * 4);
    float* score   = (float*)alloc((size_t)NG * 4);
    float* gate    = (float*)alloc((size_t)S * KSEL * 4);
    float* dinv2   = (float*)alloc((size_t)S * KSEL * 4);
    float* subemb  = (float*)alloc((size_t)S * 256 * 4);
    float* att     = (float*)alloc((size_t)S * 256 * 4);
    int*   perm    = (int*)alloc((size_t)S * KSEL * 4);
    int*   posmap  = (int*)alloc((size_t)NG * 4);
    int*   cur_sub = (int*)alloc((size_t)NG * 4);          // used as curR
    int*   rowptr_s= (int*)alloc((size_t)(NG + 64) * 4);   // alias: rowptrN
    int*   col_sub = (int*)alloc((size_t)EG * 4);          // alias: colN
    int*   rowptrR = (int*)alloc((size_t)(NG + 64) * 4);
    int*   cntR    = (int*)alloc((size_t)NG * 4);
    int*   rowlist = (int*)alloc((size_t)NG * 4);
    float* x1      = (float*)alloc((size_t)NG * NH * 4);   // alias: xsub, later X2W
    float* x2      = (float*)alloc((size_t)NG * NH * 4);
    float* hbuf    = (float*)alloc((size_t)NG * NH * 4);   // alias: hf
    float* xpool   = (float*)alloc((size_t)S * KSEL * NH * 4);  // alias: ebin
    float* xsub    = x1;
    float* hf      = hbuf;
    float* dinvN   = dinv;
    float* X2W     = x1;                                   // x1 dead after k_emb_attn
    int*   curR    = cur_sub;
    int*   rowptrN = rowptr_s;
    int*   colN    = col_sub;
    int*   ebin    = (int*)xpool;                          // 64*BCAP*4 = 5.2MB <= 16MB

    hipMemsetAsync(cntR, 0, (size_t)NG * 4, stream);

    // fused per-subgraph CSR (blocks 0-63) + countR (blocks 64-127)
    k_csr_sub<<<128, 1024, 0, stream>>>(sei, sorig, rowptr_s, col_sub, dinv, cntR);

    // GCN1 (+ fused scorer h = x1 @ Wp)
    k_matmul128<128><<<NG / 128, 256, 0, stream>>>(sub_x, W1, hbuf);
    k_agg128<true><<<8192, 256, 0, stream>>>((const float4*)hbuf, dinv, rowptr_s, col_sub,
                                             b1, Wp, (float4*)x1, scoreh);
    // GCN2
    k_matmul128<128><<<NG / 128, 256, 0, stream>>>(x1, W2, hbuf);
    k_agg128<false><<<8192, 256, 0, stream>>>((const float4*)hbuf, dinv, rowptr_s, col_sub,
                                              b2, nullptr, (float4*)x2, nullptr);
    // scorer aggregate + top-k pooling
    k_score_agg<<<NG / 256, 256, 0, stream>>>(scoreh, dinv, rowptr_s, col_sub, bp, score);
    k_topk<<<S, 512, 0, stream>>>(score, perm, gate, posmap);
    k_pool<<<(S * KSEL) / 8, 256, 0, stream>>>((const float4*)x1, perm, gate, posmap,
                                               rowptr_s, col_sub, dinv2, (float4*)xpool);
    k_emb<<<S, 1024, 0, stream>>>(xpool, subemb);
    // pooled GCN (xsub aliases x1)
    k_matmul128<128><<<(S * KSEL) / 128, 256, 0, stream>>>(xpool, Wsc, hbuf);
    k_agg_pool<<<4096, 256, 0, stream>>>((const float4*)hbuf, dinv2, perm, posmap,
                                         rowptr_s, col_sub, bsc, (float4*)xsub);
    // emb pass 2 + degenerate attention + AW = att @ Wf[128:384]
    k_emb_attn<<<S, 1024, 0, stream>>>(xsub, subemb, Wqkv, bqkv, Wo, bo, Wf, att, AW);

    // inverse-row CSR scan (fused p1+p3, inits bcur), then fillR || binN
    k_scanR<<<64, 1024, 0, stream>>>(cntR, rowptrR, curR, bcur);
    k_fbN<<<384, 256, 0, stream>>>(sorig, curR, rowlist, gei, bcur, ebin);
    // gather gemb || X2W = x2 @ Wf[0:128]
    k_gather_x2w<<<NG / 4 + NG / 64, 384, 0, stream>>>((const float4*)x2, (const float4*)att,
                                                       rowptrR, rowlist, (float4*)gemb,
                                                       x2, Wf, X2W);
    // gatherH (hf) || fillB3 (edge CSR finalize)
    k_gatherH_fB3<<<1024 + 64, 1024, 0, stream>>>((const float4*)X2W, (const float4*)AW,
                                                  rowptrR, rowlist, (float4*)hf,
                                                  ebin, bcur, rowptrN, dinvN, colN);
    // final GCN + log_softmax
    k_final<<<NG / 16, 256, 0, stream>>>((const float4*)hf, dinvN, rowptrN, colN, bfb, (float4*)out0);

    (void)in_sizes; (void)n_in; (void)out_size; (void)ws_size;
}

// Round 6
// 720.715 us; speedup vs baseline: 1.0287x; 1.0287x over previous
//
#include <hip/hip_runtime.h>
#include <math.h>

#define S     64
#define NSUB  1024
#define ESUB  16384
#define NG    65536
#define EG    1048576
#define NH    128
#define KSEL  512
#define BCAP  20480   // per-bucket ebin capacity; bucket ~ Binom(1M,1/64): mean 16384, sd 127

// ---- fused per-subgraph CSR: LDS hist + LDS scan + LDS-cursor fill (one block/subgraph)
// blocks 64..127 handle the folded countR for the node->row inverse CSR.
__global__ __launch_bounds__(1024) void k_csr_sub(const int* __restrict__ sei,
        const int* __restrict__ sorig, int* __restrict__ rowptr, int* __restrict__ col,
        float* __restrict__ dinv, int* __restrict__ cntR) {
    int b = blockIdx.x, t = threadIdx.x;
    if (b >= 64) {                                   // folded countR (NG entries)
        int r = (b - 64) * 1024 + t;
        atomicAdd(&cntR[sorig[r]], 1);
        return;
    }
    __shared__ int sh[1024];
    __shared__ int curL[1024];
    int s = b;
    curL[t] = 0;
    __syncthreads();
    const int* dstp = sei + s * 2 * ESUB + ESUB;
    #pragma unroll
    for (int k = 0; k < 16; k++) atomicAdd(&curL[dstp[k * 1024 + t]], 1);
    __syncthreads();
    int v = curL[t];
    sh[t] = v;
    __syncthreads();
    for (int off = 1; off < 1024; off <<= 1) {
        int add = (t >= off) ? sh[t - off] : 0;
        __syncthreads();
        sh[t] += add;
        __syncthreads();
    }
    int incl = sh[t];
    int excl = incl - v;
    rowptr[s * (NSUB + 1) + t] = excl;
    dinv[s * NSUB + t] = rsqrtf((float)(v + 1));     // deg = indeg + 1 (self loop)
    if (t == 1023) rowptr[s * (NSUB + 1) + NSUB] = incl;
    curL[t] = s * ESUB + excl;                       // absolute cursor
    __syncthreads();
    const int* srcp = sei + s * 2 * ESUB;
    #pragma unroll
    for (int k = 0; k < 16; k++) {
        int e = k * 1024 + t;
        int src = srcp[e];
        int dst = dstp[e];
        int p = atomicAdd(&curL[dst], 1);
        col[p] = src;
    }
}

// ---- fused scanR (p1+p3): per-block prefix self-computed; also inits bcur -----
__global__ __launch_bounds__(1024) void k_scanR(const int* __restrict__ cnt,
        int* __restrict__ rowptr, int* __restrict__ cur, int* __restrict__ bcur) {
    __shared__ int sh[1024];
    __shared__ int wsum[16];
    __shared__ int sboff;
    int b = blockIdx.x, t = threadIdx.x;
    if (b == 0 && t < 64) bcur[t] = t * BCAP;        // init for later binN reservations
    int pre = 0;
    for (int i = t; i < b * 1024; i += 1024) pre += cnt[i];
    #pragma unroll
    for (int o = 32; o > 0; o >>= 1) pre += __shfl_xor(pre, o, 64);
    if ((t & 63) == 0) wsum[t >> 6] = pre;
    __syncthreads();
    if (t == 0) {
        int r = 0;
        #pragma unroll
        for (int i = 0; i < 16; i++) r += wsum[i];
        sboff = r;
    }
    int v = cnt[b * 1024 + t];
    sh[t] = v;
    __syncthreads();
    for (int off = 1; off < 1024; off <<= 1) {
        int add = (t >= off) ? sh[t - off] : 0;
        __syncthreads();
        sh[t] += add;
        __syncthreads();
    }
    int base = sboff;
    int r = base + sh[t] - v;
    int idx = b * 1024 + t;
    rowptr[idx] = r;
    cur[idx] = r;
    if (b == 63 && t == 1023) rowptr[NG] = base + sh[t];   // = NG
}

// fillR: rowlist (pos->row) AND posR (row->pos) for producer-side permutation
__global__ void k_fillR(const int* __restrict__ orig, int* __restrict__ cur,
                        int* __restrict__ rowlist, int* __restrict__ posR) {
    int r = blockIdx.x * 256 + threadIdx.x;          // < NG
    int p = atomicAdd(&cur[orig[r]], 1);
    rowlist[p] = r;
    posR[r] = p;
}

// ---------------- tiled matmul: Y[M,NCOL] = X[M,KDIM] @ W[KDIM,NCOL] (all f32) --------
template<int KDIM, int NCOL>
__global__ __launch_bounds__(256) void k_matmul(const float* __restrict__ X,
        const float* __restrict__ W, float* __restrict__ Y) {
    __shared__ float As[16][72];
    __shared__ float Bs[16][72];
    int t = threadIdx.x;
    int row0 = blockIdx.x * 64;
    int col0 = blockIdx.y * 64;
    int tr = t >> 4, tc = t & 15;
    float acc[4][4] = {};
    for (int k0 = 0; k0 < KDIM; k0 += 16) {
        {   // stage A: 64 rows x 16 k
            int r = t >> 2, kq = t & 3;
            float4 v = *(const float4*)&X[(size_t)(row0 + r) * KDIM + k0 + kq * 4];
            As[kq * 4 + 0][r] = v.x; As[kq * 4 + 1][r] = v.y;
            As[kq * 4 + 2][r] = v.z; As[kq * 4 + 3][r] = v.w;
        }
        {   // stage B
            int k = t >> 4, cq = t & 15;
            float4 v = *(const float4*)&W[(size_t)(k0 + k) * NCOL + col0 + cq * 4];
            *(float4*)&Bs[k][cq * 4] = v;
        }
        __syncthreads();
        #pragma unroll
        for (int k = 0; k < 16; k++) {
            float a0 = As[k][tr * 4 + 0], a1 = As[k][tr * 4 + 1];
            float a2 = As[k][tr * 4 + 2], a3 = As[k][tr * 4 + 3];
            float b0 = Bs[k][tc * 4 + 0], b1 = Bs[k][tc * 4 + 1];
            float b2 = Bs[k][tc * 4 + 2], b3 = Bs[k][tc * 4 + 3];
            acc[0][0] += a0 * b0; acc[0][1] += a0 * b1; acc[0][2] += a0 * b2; acc[0][3] += a0 * b3;
            acc[1][0] += a1 * b0; acc[1][1] += a1 * b1; acc[1][2] += a1 * b2; acc[1][3] += a1 * b3;
            acc[2][0] += a2 * b0; acc[2][1] += a2 * b1; acc[2][2] += a2 * b2; acc[2][3] += a2 * b3;
            acc[3][0] += a3 * b0; acc[3][1] += a3 * b1; acc[3][2] += a3 * b2; acc[3][3] += a3 * b3;
        }
        __syncthreads();
    }
    #pragma unroll
    for (int i = 0; i < 4; i++) {
        float4 v = { acc[i][0], acc[i][1], acc[i][2], acc[i][3] };
        *(float4*)&Y[(size_t)(row0 + tr * 4 + i) * NCOL + col0 + tc * 4] = v;
    }
}

// ------- GCN aggregate (128 feats) + self + bias + relu; float4 + XCD swizzle --------
// SCORE: emit scoreh[node]. SCATTER: write out row at posR[node] (rowlist order),
// turning the later gather's random reads into streaming reads.
template<bool SCORE, bool SCATTER>
__global__ __launch_bounds__(256) void k_agg128(const float4* __restrict__ h,
        const float* __restrict__ dinv, const int* __restrict__ rowptr,
        const int* __restrict__ col, const float* __restrict__ bias,
        const float* __restrict__ Wp, const int* __restrict__ posR,
        float4* __restrict__ out, float* __restrict__ scoreh) {
    int b = blockIdx.x;
    int s = b & 63;                      // subgraph -> fixed XCD (b%8 == s%8)
    int chunk = b >> 6;
    int t = threadIdx.x;
    int nl = chunk * 8 + (t >> 5);
    int f4 = t & 31;
    const int* rp = rowptr + s * (NSUB + 1);
    int st = rp[nl], en = rp[nl + 1];
    const int* cl = col + s * ESUB;
    const float* dv = dinv + s * NSUB;
    float4 acc = {0.f, 0.f, 0.f, 0.f};
    for (int p = st; p < en; p++) {
        int src = cl[p];
        float d = dv[src];
        float4 hv = h[((size_t)(s * NSUB + src)) * 32 + f4];
        acc.x += hv.x * d; acc.y += hv.y * d; acc.z += hv.z * d; acc.w += hv.w * d;
    }
    size_t node = (size_t)s * NSUB + nl;
    float dn = dv[nl];
    float dn2 = dn * dn;
    float4 hs = h[node * 32 + f4];
    float4 bb = ((const float4*)bias)[f4];
    float4 r;
    r.x = fmaxf(acc.x * dn + hs.x * dn2 + bb.x, 0.f);
    r.y = fmaxf(acc.y * dn + hs.y * dn2 + bb.y, 0.f);
    r.z = fmaxf(acc.z * dn + hs.z * dn2 + bb.z, 0.f);
    r.w = fmaxf(acc.w * dn + hs.w * dn2 + bb.w, 0.f);
    size_t orow = SCATTER ? (size_t)posR[node] : node;
    out[orow * 32 + f4] = r;
    if (SCORE) {
        float4 wp = ((const float4*)Wp)[f4];
        float p = r.x * wp.x + r.y * wp.y + r.z * wp.z + r.w * wp.w;
        #pragma unroll
        for (int o = 16; o > 0; o >>= 1) p += __shfl_xor(p, o, 32);
        if (f4 == 0) scoreh[node] = p;
    }
}

__global__ void k_score_agg(const float* __restrict__ sh, const float* __restrict__ dinv,
                            const int* __restrict__ rowptr, const int* __restrict__ col,
                            const float* __restrict__ bp, float* __restrict__ score) {
    int n = blockIdx.x * 256 + threadIdx.x;
    int s = n >> 10, nl = n & (NSUB - 1);
    const int* rp = rowptr + s * (NSUB + 1);
    const int* cl = col + s * ESUB;
    const float* dv = dinv + s * NSUB;
    int st = rp[nl], en = rp[nl + 1];
    float acc = 0.f;
    for (int p = st; p < en; p++) {
        int src = cl[p];
        acc += sh[s * NSUB + src] * dv[src];
    }
    float dn = dv[nl];
    score[n] = acc * dn + sh[n] * dn * dn + bp[0];
}

// ---------------- per-subgraph top-K (bitonic; set-invariant downstream) -----
__global__ __launch_bounds__(512) void k_topk(const float* __restrict__ score,
        int* __restrict__ perm, float* __restrict__ gate, int* __restrict__ posmap) {
    __shared__ float sv[1024];
    __shared__ int   si[1024];
    int s = blockIdx.x, t = threadIdx.x;
    for (int i = t; i < 1024; i += 512) {
        sv[i] = score[s * NSUB + i];
        si[i] = i;
        posmap[s * NSUB + i] = -1;
    }
    __syncthreads();
    for (int k = 2; k <= 1024; k <<= 1) {
        for (int j = k >> 1; j > 0; j >>= 1) {
            for (int b = t; b < 1024; b += 512) {
                int ixj = b ^ j;
                if (ixj > b) {
                    bool desc = ((b & k) == 0);
                    bool sw = desc ? (sv[b] < sv[ixj]) : (sv[b] > sv[ixj]);
                    if (sw) {
                        float tv = sv[b]; sv[b] = sv[ixj]; sv[ixj] = tv;
                        int ti = si[b]; si[b] = si[ixj]; si[ixj] = ti;
                    }
                }
            }
            __syncthreads();
        }
    }
    if (t < KSEL) {
        perm[s * KSEL + t] = si[t];
        gate[s * KSEL + t] = tanhf(sv[t]);
        posmap[s * NSUB + si[t]] = t;
    }
}

// fused deg2 + xpool
__global__ __launch_bounds__(256) void k_pool(const float4* __restrict__ x1,
        const int* __restrict__ perm, const float* __restrict__ gate,
        const int* __restrict__ posmap, const int* __restrict__ rowptr,
        const int* __restrict__ col, float* __restrict__ dinv2,
        float4* __restrict__ xpool) {
    int t = threadIdx.x;
    int i = blockIdx.x * 8 + (t >> 5);
    int lane = t & 31;
    int s = i >> 9;
    int n = perm[i];
    const int* rp = rowptr + s * (NSUB + 1);
    const int* cl = col + s * ESUB;
    int st = rp[n], en = rp[n + 1];
    int c = 0;
    for (int p = st + lane; p < en; p += 32) c += (posmap[s * NSUB + cl[p]] >= 0) ? 1 : 0;
    #pragma unroll
    for (int o = 16; o > 0; o >>= 1) c += __shfl_xor(c, o, 32);
    if (lane == 0) dinv2[i] = rsqrtf((float)(c + 1));
    float g = gate[i];
    float4 v = x1[((size_t)(s * NSUB + n)) * 32 + lane];
    v.x *= g; v.y *= g; v.z *= g; v.w *= g;
    xpool[(size_t)i * 32 + lane] = v;
}

// max/mean over 512 rows -> [256] per subgraph
__global__ __launch_bounds__(1024) void k_emb(const float* __restrict__ X,
        float* __restrict__ out) {
    __shared__ float red[4][256];
    int s = blockIdx.x, t = threadIdx.x;
    int sl = t >> 8, f = t & 255;
    const float* base = X + (size_t)s * KSEL * NH;
    float r;
    if (f < NH) {
        r = -INFINITY;
        for (int i = sl * 128; i < sl * 128 + 128; i++) r = fmaxf(r, base[i * NH + f]);
    } else {
        r = 0.f;
        for (int i = sl * 128; i < sl * 128 + 128; i++) r += base[i * NH + (f - NH)];
    }
    red[sl][f] = r;
    __syncthreads();
    if (sl == 0) {
        float a = red[0][f], b = red[1][f], c = red[2][f], d = red[3][f];
        float v = (f < NH) ? fmaxf(fmaxf(a, b), fmaxf(c, d)) : (a + b + c + d) * (1.f / KSEL);
        out[s * 256 + f] = v;
    }
}

// emb pass 2 + degenerate attention + AW = att @ Wf[128:384]
__global__ __launch_bounds__(1024) void k_emb_attn(const float* __restrict__ X,
        const float* __restrict__ subemb, const float* __restrict__ Wqkv,
        const float* __restrict__ bqkv, const float* __restrict__ Wo,
        const float* __restrict__ bo, const float* __restrict__ Wf,
        float* __restrict__ att, float* __restrict__ AW) {
    __shared__ float red[4][256];
    __shared__ float se[256], t1[256], av[256];
    int s = blockIdx.x, t = threadIdx.x;
    int sl = t >> 8, f = t & 255;
    const float* base = X + (size_t)s * KSEL * NH;
    float r;
    if (f < NH) {
        r = -INFINITY;
        for (int i = sl * 128; i < sl * 128 + 128; i++) r = fmaxf(r, base[i * NH + f]);
    } else {
        r = 0.f;
        for (int i = sl * 128; i < sl * 128 + 128; i++) r += base[i * NH + (f - NH)];
    }
    red[sl][f] = r;
    __syncthreads();
    if (sl == 0) {
        float a = red[0][f], b = red[1][f], c = red[2][f], d = red[3][f];
        float v = (f < NH) ? fmaxf(fmaxf(a, b), fmaxf(c, d)) : (a + b + c + d) * (1.f / KSEL);
        se[f] = subemb[s * 256 + f] + v;
    }
    __syncthreads();
    if (sl == 0) {
        float acc = bqkv[512 + f];
        for (int k = 0; k < 256; k++) acc += se[k] * Wqkv[(size_t)k * 768 + 512 + f];
        t1[f] = acc;
    }
    __syncthreads();
    if (sl == 0) {
        float a2 = bo[f];
        for (int k = 0; k < 256; k++) a2 += t1[k] * Wo[(size_t)k * 256 + f];
        att[s * 256 + f] = a2;
        av[f] = a2;
    }
    __syncthreads();
    if (sl == 0 && f < 64) {
        float acc = 0.f;
        for (int k = 0; k < 256; k++) acc += av[k] * Wf[(size_t)(NH + k) * 64 + f];
        AW[s * 64 + f] = acc;
    }
}

// pooled GCN aggregate
__global__ __launch_bounds__(256) void k_agg_pool(const float4* __restrict__ hp,
        const float* __restrict__ dinv2, const int* __restrict__ perm,
        const int* __restrict__ posmap, const int* __restrict__ rowptr,
        const int* __restrict__ col, const float* __restrict__ bsc,
        float4* __restrict__ xsub) {
    int b = blockIdx.x;
    int s = b & 63;
    int chunk = b >> 6;
    int t = threadIdx.x;
    int il = chunk * 8 + (t >> 5);
    int f4 = t & 31;
    int i = s * KSEL + il;
    int n = perm[i];
    const int* rp = rowptr + s * (NSUB + 1);
    const int* cl = col + s * ESUB;
    int st = rp[n], en = rp[n + 1];
    float4 acc = {0.f, 0.f, 0.f, 0.f};
    for (int p = st; p < en; p++) {
        int j = posmap[s * NSUB + cl[p]];
        if (j >= 0) {
            float d = dinv2[s * KSEL + j];
            float4 hv = hp[((size_t)(s * KSEL + j)) * 32 + f4];
            acc.x += hv.x * d; acc.y += hv.y * d; acc.z += hv.z * d; acc.w += hv.w * d;
        }
    }
    float dn = dinv2[i];
    float dn2 = dn * dn;
    float4 hs = hp[(size_t)i * 32 + f4];
    float4 bb = ((const float4*)bsc)[f4];
    float4 r;
    r.x = fmaxf(acc.x * dn + hs.x * dn2 + bb.x, 0.f);
    r.y = fmaxf(acc.y * dn + hs.y * dn2 + bb.y, 0.f);
    r.z = fmaxf(acc.z * dn + hs.z * dn2 + bb.z, 0.f);
    r.w = fmaxf(acc.w * dn + hs.w * dn2 + bb.w, 0.f);
    xsub[(size_t)i * 32 + f4] = r;
}

// streaming gather: x2s is already in rowlist order -> sequential reads.
// lanes 0-31: node features; lanes 32-95: att broadcast (sub via L2-hot rowlist).
__global__ __launch_bounds__(384) void k_gather(const float4* __restrict__ x2s,
        const float4* __restrict__ att, const int* __restrict__ rowptrR,
        const int* __restrict__ rowlist, float4* __restrict__ gemb) {
    int t = threadIdx.x;
    int g = blockIdx.x * 4 + (t / 96);               // 4 nodes / block
    int lane = t % 96;                               // 96 float4 = 384 feats
    int st = rowptrR[g], en = rowptrR[g + 1];
    float4 acc = {0.f, 0.f, 0.f, 0.f};
    if (lane < 32) {
        for (int p = st; p < en; p++) {
            float4 v = x2s[(size_t)p * 32 + lane];
            acc.x += v.x; acc.y += v.y; acc.z += v.z; acc.w += v.w;
        }
    } else {
        for (int p = st; p < en; p++) {
            int sub = rowlist[p] >> 10;
            float4 v = att[(size_t)sub * 64 + (lane - 32)];
            acc.x += v.x; acc.y += v.y; acc.z += v.z; acc.w += v.w;
        }
    }
    gemb[(size_t)g * 96 + lane] = acc;
}

// X2Ws[p] = x2s[p] @ Wf[0:128] + AW[sub(rowlist[p])]   (64x64 tile, K=128 NCOL=64)
__global__ __launch_bounds__(256) void k_x2w(const float* __restrict__ X,
        const float* __restrict__ W, const int* __restrict__ rowlist,
        const float* __restrict__ AW, float* __restrict__ Y) {
    __shared__ float As[16][72];
    __shared__ float Bs[16][72];
    int t = threadIdx.x;
    int row0 = blockIdx.x * 64;
    int tr = t >> 4, tc = t & 15;
    float acc[4][4] = {};
    for (int k0 = 0; k0 < 128; k0 += 16) {
        {   int r = t >> 2, kq = t & 3;
            float4 v = *(const float4*)&X[(size_t)(row0 + r) * 128 + k0 + kq * 4];
            As[kq * 4 + 0][r] = v.x; As[kq * 4 + 1][r] = v.y;
            As[kq * 4 + 2][r] = v.z; As[kq * 4 + 3][r] = v.w;
        }
        {   int k = t >> 4, cq = t & 15;
            float4 v = *(const float4*)&W[(size_t)(k0 + k) * 64 + cq * 4];
            *(float4*)&Bs[k][cq * 4] = v;
        }
        __syncthreads();
        #pragma unroll
        for (int k = 0; k < 16; k++) {
            float a0 = As[k][tr * 4 + 0], a1 = As[k][tr * 4 + 1];
            float a2 = As[k][tr * 4 + 2], a3 = As[k][tr * 4 + 3];
            float b0 = Bs[k][tc * 4 + 0], b1 = Bs[k][tc * 4 + 1];
            float b2 = Bs[k][tc * 4 + 2], b3 = Bs[k][tc * 4 + 3];
            acc[0][0] += a0 * b0; acc[0][1] += a0 * b1; acc[0][2] += a0 * b2; acc[0][3] += a0 * b3;
            acc[1][0] += a1 * b0; acc[1][1] += a1 * b1; acc[1][2] += a1 * b2; acc[1][3] += a1 * b3;
            acc[2][0] += a2 * b0; acc[2][1] += a2 * b1; acc[2][2] += a2 * b2; acc[2][3] += a2 * b3;
            acc[3][0] += a3 * b0; acc[3][1] += a3 * b1; acc[3][2] += a3 * b2; acc[3][3] += a3 * b3;
        }
        __syncthreads();
    }
    #pragma unroll
    for (int i = 0; i < 4; i++) {
        int rr = row0 + tr * 4 + i;
        int sub = rowlist[rr] >> 10;
        const float4 aw = *(const float4*)&AW[(size_t)sub * 64 + tc * 4];
        float4 v = { acc[i][0] + aw.x, acc[i][1] + aw.y, acc[i][2] + aw.z, acc[i][3] + aw.w };
        *(float4*)&Y[(size_t)rr * 64 + tc * 4] = v;
    }
}

// hf[g] = sum_p X2Ws[p]  -- pure streaming segmented sum
__global__ __launch_bounds__(256) void k_gatherH(const float4* __restrict__ X2Ws,
        const int* __restrict__ rowptrR, float4* __restrict__ hf) {
    int t = threadIdx.x;
    int g = blockIdx.x * 16 + (t >> 4);
    int f4 = t & 15;
    int st = rowptrR[g], en = rowptrR[g + 1];
    float4 acc = {0.f, 0.f, 0.f, 0.f};
    for (int p = st; p < en; p++) {
        float4 a = X2Ws[(size_t)p * 16 + f4];
        acc.x += a.x; acc.y += a.y; acc.z += a.z; acc.w += a.w;
    }
    hf[(size_t)g * 16 + f4] = acc;
}

// ---------------- global edge CSR: bin (fixed-capacity buckets) + fused fill --------
__global__ __launch_bounds__(256) void k_binN(const int* __restrict__ gei,
        int* __restrict__ bcur, int* __restrict__ ebin) {
    __shared__ int lh[64];
    __shared__ int lbase[64];
    int t = threadIdx.x;
    if (t < 64) lh[t] = 0;
    __syncthreads();
    int e0 = blockIdx.x * 8192;
    #pragma unroll 8
    for (int k = 0; k < 32; k++) {
        int d = gei[EG + e0 + k * 256 + t];
        atomicAdd(&lh[d >> 10], 1);
    }
    __syncthreads();
    if (t < 64) {
        lbase[t] = atomicAdd(&bcur[t], lh[t]);
        lh[t] = 0;
    }
    __syncthreads();
    #pragma unroll 4
    for (int k = 0; k < 32; k++) {
        int idx = e0 + k * 256 + t;
        int d = gei[EG + idx];
        int src = gei[idx];
        int bb = d >> 10;
        int pos = lbase[bb] + atomicAdd(&lh[bb], 1);
        ebin[pos] = src | ((d & 1023) << 16);
    }
}

// one block per bucket: LDS hist/scan -> rowptrN/dinvN, then LDS-cursor fill of colN
__global__ __launch_bounds__(1024) void k_fillB3(const int* __restrict__ ebin,
        const int* __restrict__ bcur, int* __restrict__ rowptrN,
        float* __restrict__ dinvN, int* __restrict__ colN) {
    __shared__ int sh[1024];
    __shared__ int curL[1024];
    __shared__ int sbase;
    int b = blockIdx.x, t = threadIdx.x;
    if (t == 0) {
        int run = 0;
        for (int i = 0; i < b; i++) run += bcur[i] - i * BCAP;
        sbase = run;
    }
    curL[t] = 0;
    __syncthreads();
    int st = b * BCAP, en = bcur[b];
    for (int i = st + t; i < en; i += 1024) atomicAdd(&curL[ebin[i] >> 16], 1);
    __syncthreads();
    int v = curL[t];
    sh[t] = v;
    __syncthreads();
    for (int off = 1; off < 1024; off <<= 1) {
        int add = (t >= off) ? sh[t - off] : 0;
        __syncthreads();
        sh[t] += add;
        __syncthreads();
    }
    int incl = sh[t];
    int excl = incl - v;
    int base = sbase;
    rowptrN[(b << 10) + t] = base + excl;
    dinvN[(b << 10) + t] = rsqrtf((float)(v + 1));
    if (b == 63 && t == 1023) rowptrN[NG] = base + incl;   // = EG
    curL[t] = base + excl;
    __syncthreads();
    for (int i = st + t; i < en; i += 1024) {
        int packed = ebin[i];
        int p = atomicAdd(&curL[packed >> 16], 1);
        colN[p] = packed & 0xFFFF;
    }
}

// final GCN aggregate + bias + log_softmax (64 classes = 16 float4 lanes)
__global__ __launch_bounds__(256) void k_final(const float4* __restrict__ hf,
        const float* __restrict__ dinvN, const int* __restrict__ rowptr,
        const int* __restrict__ col, const float* __restrict__ bfb,
        float4* __restrict__ out) {
    int t = threadIdx.x;
    int n = blockIdx.x * 16 + (t >> 4);
    int f4 = t & 15;
    int st = rowptr[n], en = rowptr[n + 1];
    float4 acc = {0.f, 0.f, 0.f, 0.f};
    for (int p = st; p < en; p++) {
        int src = col[p];
        float d = dinvN[src];
        float4 hv = hf[(size_t)src * 16 + f4];
        acc.x += hv.x * d; acc.y += hv.y * d; acc.z += hv.z * d; acc.w += hv.w * d;
    }
    float dn = dinvN[n];
    float dn2 = dn * dn;
    float4 hs = hf[(size_t)n * 16 + f4];
    float4 bb = ((const float4*)bfb)[f4];
    float4 x;
    x.x = acc.x * dn + hs.x * dn2 + bb.x;
    x.y = acc.y * dn + hs.y * dn2 + bb.y;
    x.z = acc.z * dn + hs.z * dn2 + bb.z;
    x.w = acc.w * dn + hs.w * dn2 + bb.w;
    float m = fmaxf(fmaxf(x.x, x.y), fmaxf(x.z, x.w));
    for (int o = 1; o < 16; o <<= 1) m = fmaxf(m, __shfl_xor(m, o, 64));
    float ssum = expf(x.x - m) + expf(x.y - m) + expf(x.z - m) + expf(x.w - m);
    for (int o = 1; o < 16; o <<= 1) ssum += __shfl_xor(ssum, o, 64);
    float lz = m + logf(ssum);
    float4 r = { x.x - lz, x.y - lz, x.z - lz, x.w - lz };
    out[(size_t)n * 16 + f4] = r;
}

// ---------------- host ----------------
extern "C" void kernel_launch(void* const* d_in, const int* in_sizes, int n_in,
                              void* d_out, int out_size, void* d_ws, size_t ws_size,
                              hipStream_t stream) {
    const float* sub_x = (const float*)d_in[0];
    const int*   sei   = (const int*)d_in[1];
    const int*   sorig = (const int*)d_in[2];
    const int*   gei   = (const int*)d_in[3];
    const float *W1 = (const float*)d_in[4],  *b1  = (const float*)d_in[5];
    const float *W2 = (const float*)d_in[6],  *b2  = (const float*)d_in[7];
    const float *Wp = (const float*)d_in[8],  *bp  = (const float*)d_in[9];
    const float *Wsc = (const float*)d_in[10], *bsc = (const float*)d_in[11];
    const float *Wqkv = (const float*)d_in[12], *bqkv = (const float*)d_in[13];
    const float *Wo = (const float*)d_in[14], *bo  = (const float*)d_in[15];
    const float *Wf = (const float*)d_in[16], *bfb = (const float*)d_in[17];

    float* out0 = (float*)d_out;                      // log-softmax [NG,64]
    float* gemb = (float*)d_out + (size_t)NG * 64;    // global_emb [NG,384] in-place

    char* w = (char*)d_ws;
    size_t off = 0;
    auto alloc = [&](size_t nbytes) -> void* {
        off = (off + 255) & ~(size_t)255;
        void* p = w + off;
        off += nbytes;
        return p;
    };
    int*   bcur    = (int*)alloc(64 * 4);
    float* AW      = (float*)alloc((size_t)S * 64 * 4);
    float* dinv    = (float*)alloc((size_t)NG * 4);        // subgraph dinv; later dinvN
    float* scoreh  = (float*)alloc((size_t)NG * 4);
    float* score   = (float*)alloc((size_t)NG * 4);
    float* gate    = (float*)alloc((size_t)S * KSEL * 4);
    float* dinv2   = (float*)alloc((size_t)S * KSEL * 4);
    float* subemb  = (float*)alloc((size_t)S * 256 * 4);
    float* att     = (float*)alloc((size_t)S * 256 * 4);
    int*   perm    = (int*)alloc((size_t)S * KSEL * 4);
    int*   posmap  = (int*)alloc((size_t)NG * 4);
    int*   cur_sub = (int*)alloc((size_t)NG * 4);          // used as curR
    int*   rowptr_s= (int*)alloc((size_t)(NG + 64) * 4);   // alias: rowptrN
    int*   col_sub = (int*)alloc((size_t)EG * 4);          // alias: colN
    int*   rowptrR = (int*)alloc((size_t)(NG + 64) * 4);
    int*   cntR    = (int*)alloc((size_t)NG * 4);
    int*   rowlist = (int*)alloc((size_t)NG * 4);
    int*   posR    = (int*)alloc((size_t)NG * 4);
    float* x1      = (float*)alloc((size_t)NG * NH * 4);   // alias: xsub, later X2Ws
    float* x2s     = (float*)alloc((size_t)NG * NH * 4);   // GCN2 out, PERMUTED to rowlist order
    float* hbuf    = (float*)alloc((size_t)NG * NH * 4);   // alias: hf
    float* xpool   = (float*)alloc((size_t)S * KSEL * NH * 4);  // alias: ebin
    float* xsub    = x1;
    float* hf      = hbuf;
    float* dinvN   = dinv;
    float* X2Ws    = x1;                                   // x1 dead after k_emb_attn
    int*   curR    = cur_sub;
    int*   rowptrN = rowptr_s;
    int*   colN    = col_sub;
    int*   ebin    = (int*)xpool;                          // xpool dead after mm_pool

    hipMemsetAsync(cntR, 0, (size_t)NG * 4, stream);

    // per-subgraph CSR (blocks 0-63) + countR (blocks 64-127); then inverse-row CSR
    // EARLY so posR is ready for GCN2's producer-side permutation.
    k_csr_sub<<<128, 1024, 0, stream>>>(sei, sorig, rowptr_s, col_sub, dinv, cntR);
    k_scanR<<<64, 1024, 0, stream>>>(cntR, rowptrR, curR, bcur);
    k_fillR<<<NG / 256, 256, 0, stream>>>(sorig, curR, rowlist, posR);

    // GCN1 (+ fused scorer h = x1 @ Wp)
    k_matmul<128, 128><<<dim3(NG / 64, 2), 256, 0, stream>>>(sub_x, W1, hbuf);
    k_agg128<true, false><<<8192, 256, 0, stream>>>((const float4*)hbuf, dinv, rowptr_s,
                                                    col_sub, b1, Wp, nullptr, (float4*)x1, scoreh);
    // GCN2 -> x2s written in rowlist order (scatter-write; streaming reads downstream)
    k_matmul<128, 128><<<dim3(NG / 64, 2), 256, 0, stream>>>(x1, W2, hbuf);
    k_agg128<false, true><<<8192, 256, 0, stream>>>((const float4*)hbuf, dinv, rowptr_s,
                                                    col_sub, b2, nullptr, posR, (float4*)x2s, nullptr);
    // scorer aggregate + top-k pooling
    k_score_agg<<<NG / 256, 256, 0, stream>>>(scoreh, dinv, rowptr_s, col_sub, bp, score);
    k_topk<<<S, 512, 0, stream>>>(score, perm, gate, posmap);
    k_pool<<<(S * KSEL) / 8, 256, 0, stream>>>((const float4*)x1, perm, gate, posmap,
                                               rowptr_s, col_sub, dinv2, (float4*)xpool);
    k_emb<<<S, 1024, 0, stream>>>(xpool, subemb);
    // pooled GCN (xsub aliases x1)
    k_matmul<128, 128><<<dim3((S * KSEL) / 64, 2), 256, 0, stream>>>(xpool, Wsc, hbuf);
    k_agg_pool<<<4096, 256, 0, stream>>>((const float4*)hbuf, dinv2, perm, posmap,
                                         rowptr_s, col_sub, bsc, (float4*)xsub);
    // emb pass 2 + degenerate attention + AW = att @ Wf[128:384]
    k_emb_attn<<<S, 1024, 0, stream>>>(xsub, subemb, Wqkv, bqkv, Wo, bo, Wf, att, AW);

    // global edge CSR (ebin aliases xpool -> safe after mm_pool)
    k_binN<<<EG / 8192, 256, 0, stream>>>(gei, bcur, ebin);
    k_fillB3<<<64, 1024, 0, stream>>>(ebin, bcur, rowptrN, dinvN, colN);

    // streaming gather of gemb; X2Ws matmul (+AW fold); streaming hf sum
    k_gather<<<NG / 4, 384, 0, stream>>>((const float4*)x2s, (const float4*)att,
                                         rowptrR, rowlist, (float4*)gemb);
    k_x2w<<<NG / 64, 256, 0, stream>>>(x2s, Wf, rowlist, AW, X2Ws);
    k_gatherH<<<NG / 16, 256, 0, stream>>>((const float4*)X2Ws, rowptrR, (float4*)hf);

    // final GCN + log_softmax
    k_final<<<NG / 16, 256, 0, stream>>>((const float4*)hf, dinvN, rowptrN, colN, bfb, (float4*)out0);

    (void)in_sizes; (void)n_in; (void)out_size; (void)ws_size;
}

// Round 7
// 682.137 us; speedup vs baseline: 1.0869x; 1.0566x over previous
//
#include <hip/hip_runtime.h>
#include <math.h>

#define S     64
#define NSUB  1024
#define ESUB  16384
#define NG    65536
#define EG    1048576
#define NH    128
#define KSEL  512
#define BCAP  20480   // per-bucket ebin capacity; bucket ~ Binom(1M,1/64): mean 16384, sd 127

// ---- fused per-subgraph CSR: LDS hist + LDS scan + LDS-cursor fill (one block/subgraph)
// blocks 64..127 handle the folded countR for the node->row inverse CSR.
__global__ __launch_bounds__(1024) void k_csr_sub(const int* __restrict__ sei,
        const int* __restrict__ sorig, int* __restrict__ rowptr, int* __restrict__ col,
        float* __restrict__ dinv, int* __restrict__ cntR) {
    int b = blockIdx.x, t = threadIdx.x;
    if (b >= 64) {                                   // folded countR (NG entries)
        int r = (b - 64) * 1024 + t;
        atomicAdd(&cntR[sorig[r]], 1);
        return;
    }
    __shared__ int sh[1024];
    __shared__ int curL[1024];
    int s = b;
    curL[t] = 0;
    __syncthreads();
    const int* dstp = sei + s * 2 * ESUB + ESUB;
    #pragma unroll
    for (int k = 0; k < 16; k++) atomicAdd(&curL[dstp[k * 1024 + t]], 1);
    __syncthreads();
    int v = curL[t];
    sh[t] = v;
    __syncthreads();
    for (int off = 1; off < 1024; off <<= 1) {
        int add = (t >= off) ? sh[t - off] : 0;
        __syncthreads();
        sh[t] += add;
        __syncthreads();
    }
    int incl = sh[t];
    int excl = incl - v;
    rowptr[s * (NSUB + 1) + t] = excl;
    dinv[s * NSUB + t] = rsqrtf((float)(v + 1));     // deg = indeg + 1 (self loop)
    if (t == 1023) rowptr[s * (NSUB + 1) + NSUB] = incl;
    curL[t] = s * ESUB + excl;                       // absolute cursor
    __syncthreads();
    const int* srcp = sei + s * 2 * ESUB;
    #pragma unroll
    for (int k = 0; k < 16; k++) {
        int e = k * 1024 + t;
        int src = srcp[e];
        int dst = dstp[e];
        int p = atomicAdd(&curL[dst], 1);
        col[p] = src;
    }
}

// ---- fused scanR (p1+p3): per-block prefix self-computed ------------------
__global__ __launch_bounds__(1024) void k_scanR(const int* __restrict__ cnt,
        int* __restrict__ rowptr, int* __restrict__ cur) {
    __shared__ int sh[1024];
    __shared__ int wsum[16];
    __shared__ int sboff;
    int b = blockIdx.x, t = threadIdx.x;
    int pre = 0;
    for (int i = t; i < b * 1024; i += 1024) pre += cnt[i];
    #pragma unroll
    for (int o = 32; o > 0; o >>= 1) pre += __shfl_xor(pre, o, 64);
    if ((t & 63) == 0) wsum[t >> 6] = pre;
    __syncthreads();
    if (t == 0) {
        int r = 0;
        #pragma unroll
        for (int i = 0; i < 16; i++) r += wsum[i];
        sboff = r;
    }
    int v = cnt[b * 1024 + t];
    sh[t] = v;
    __syncthreads();
    for (int off = 1; off < 1024; off <<= 1) {
        int add = (t >= off) ? sh[t - off] : 0;
        __syncthreads();
        sh[t] += add;
        __syncthreads();
    }
    int base = sboff;
    int r = base + sh[t] - v;
    int idx = b * 1024 + t;
    rowptr[idx] = r;
    cur[idx] = r;
    if (b == 63 && t == 1023) rowptr[NG] = base + sh[t];   // = NG
}

// fillR: rowlist (pos->row) AND posR (row->pos) for producer-side permutation
__global__ void k_fillR(const int* __restrict__ orig, int* __restrict__ cur,
                        int* __restrict__ rowlist, int* __restrict__ posR) {
    int r = blockIdx.x * 256 + threadIdx.x;          // < NG
    int p = atomicAdd(&cur[orig[r]], 1);
    rowlist[p] = r;
    posR[r] = p;
}

// ---------------- tiled matmul: Y[M,NCOL] = X[M,KDIM] @ W[KDIM,NCOL] (all f32) --------
template<int KDIM, int NCOL>
__global__ __launch_bounds__(256) void k_matmul(const float* __restrict__ X,
        const float* __restrict__ W, float* __restrict__ Y) {
    __shared__ float As[16][72];
    __shared__ float Bs[16][72];
    int t = threadIdx.x;
    int row0 = blockIdx.x * 64;
    int col0 = blockIdx.y * 64;
    int tr = t >> 4, tc = t & 15;
    float acc[4][4] = {};
    for (int k0 = 0; k0 < KDIM; k0 += 16) {
        {   int r = t >> 2, kq = t & 3;
            float4 v = *(const float4*)&X[(size_t)(row0 + r) * KDIM + k0 + kq * 4];
            As[kq * 4 + 0][r] = v.x; As[kq * 4 + 1][r] = v.y;
            As[kq * 4 + 2][r] = v.z; As[kq * 4 + 3][r] = v.w;
        }
        {   int k = t >> 4, cq = t & 15;
            float4 v = *(const float4*)&W[(size_t)(k0 + k) * NCOL + col0 + cq * 4];
            *(float4*)&Bs[k][cq * 4] = v;
        }
        __syncthreads();
        #pragma unroll
        for (int k = 0; k < 16; k++) {
            float a0 = As[k][tr * 4 + 0], a1 = As[k][tr * 4 + 1];
            float a2 = As[k][tr * 4 + 2], a3 = As[k][tr * 4 + 3];
            float b0 = Bs[k][tc * 4 + 0], b1 = Bs[k][tc * 4 + 1];
            float b2 = Bs[k][tc * 4 + 2], b3 = Bs[k][tc * 4 + 3];
            acc[0][0] += a0 * b0; acc[0][1] += a0 * b1; acc[0][2] += a0 * b2; acc[0][3] += a0 * b3;
            acc[1][0] += a1 * b0; acc[1][1] += a1 * b1; acc[1][2] += a1 * b2; acc[1][3] += a1 * b3;
            acc[2][0] += a2 * b0; acc[2][1] += a2 * b1; acc[2][2] += a2 * b2; acc[2][3] += a2 * b3;
            acc[3][0] += a3 * b0; acc[3][1] += a3 * b1; acc[3][2] += a3 * b2; acc[3][3] += a3 * b3;
        }
        __syncthreads();
    }
    #pragma unroll
    for (int i = 0; i < 4; i++) {
        float4 v = { acc[i][0], acc[i][1], acc[i][2], acc[i][3] };
        *(float4*)&Y[(size_t)(row0 + tr * 4 + i) * NCOL + col0 + tc * 4] = v;
    }
}

// ---- fused: blocks [0,2048) matmul2 (128x128, flattened); [2048,2304) score_agg ----
__global__ __launch_bounds__(256) void k_mm2s(const float* __restrict__ X,
        const float* __restrict__ W, float* __restrict__ Y,
        const float* __restrict__ sh, const float* __restrict__ dinv,
        const int* __restrict__ rowptr, const int* __restrict__ col,
        const float* __restrict__ bp, float* __restrict__ score) {
    int t = threadIdx.x;
    if (blockIdx.x >= 2048) {                        // score_agg
        int n = (blockIdx.x - 2048) * 256 + t;
        int s = n >> 10, nl = n & (NSUB - 1);
        const int* rp = rowptr + s * (NSUB + 1);
        const int* cl = col + s * ESUB;
        const float* dv = dinv + s * NSUB;
        int st = rp[nl], en = rp[nl + 1];
        float acc = 0.f;
        for (int p = st; p < en; p++) {
            int src = cl[p];
            acc += sh[s * NSUB + src] * dv[src];
        }
        float dn = dv[nl];
        score[n] = acc * dn + sh[n] * dn * dn + bp[0];
        return;
    }
    __shared__ float As[16][72];
    __shared__ float Bs[16][72];
    int row0 = (blockIdx.x & 1023) * 64;
    int col0 = (blockIdx.x >> 10) * 64;
    int tr = t >> 4, tc = t & 15;
    float acc[4][4] = {};
    for (int k0 = 0; k0 < 128; k0 += 16) {
        {   int r = t >> 2, kq = t & 3;
            float4 v = *(const float4*)&X[(size_t)(row0 + r) * 128 + k0 + kq * 4];
            As[kq * 4 + 0][r] = v.x; As[kq * 4 + 1][r] = v.y;
            As[kq * 4 + 2][r] = v.z; As[kq * 4 + 3][r] = v.w;
        }
        {   int k = t >> 4, cq = t & 15;
            float4 v = *(const float4*)&W[(size_t)(k0 + k) * 128 + col0 + cq * 4];
            *(float4*)&Bs[k][cq * 4] = v;
        }
        __syncthreads();
        #pragma unroll
        for (int k = 0; k < 16; k++) {
            float a0 = As[k][tr * 4 + 0], a1 = As[k][tr * 4 + 1];
            float a2 = As[k][tr * 4 + 2], a3 = As[k][tr * 4 + 3];
            float b0 = Bs[k][tc * 4 + 0], b1 = Bs[k][tc * 4 + 1];
            float b2 = Bs[k][tc * 4 + 2], b3 = Bs[k][tc * 4 + 3];
            acc[0][0] += a0 * b0; acc[0][1] += a0 * b1; acc[0][2] += a0 * b2; acc[0][3] += a0 * b3;
            acc[1][0] += a1 * b0; acc[1][1] += a1 * b1; acc[1][2] += a1 * b2; acc[1][3] += a1 * b3;
            acc[2][0] += a2 * b0; acc[2][1] += a2 * b1; acc[2][2] += a2 * b2; acc[2][3] += a2 * b3;
            acc[3][0] += a3 * b0; acc[3][1] += a3 * b1; acc[3][2] += a3 * b2; acc[3][3] += a3 * b3;
        }
        __syncthreads();
    }
    #pragma unroll
    for (int i = 0; i < 4; i++) {
        float4 v = { acc[i][0], acc[i][1], acc[i][2], acc[i][3] };
        *(float4*)&Y[(size_t)(row0 + tr * 4 + i) * 128 + col0 + tc * 4] = v;
    }
}

// ------- GCN aggregate (128 feats) + self + bias + relu; float4 + XCD swizzle --------
// SCORE: emit scoreh[node]. SCATTER: write out row at posR[node] (rowlist order).
template<bool SCORE, bool SCATTER>
__global__ __launch_bounds__(256) void k_agg128(const float4* __restrict__ h,
        const float* __restrict__ dinv, const int* __restrict__ rowptr,
        const int* __restrict__ col, const float* __restrict__ bias,
        const float* __restrict__ Wp, const int* __restrict__ posR,
        float4* __restrict__ out, float* __restrict__ scoreh) {
    int b = blockIdx.x;
    int s = b & 63;                      // subgraph -> fixed XCD (b%8 == s%8)
    int chunk = b >> 6;
    int t = threadIdx.x;
    int nl = chunk * 8 + (t >> 5);
    int f4 = t & 31;
    const int* rp = rowptr + s * (NSUB + 1);
    int st = rp[nl], en = rp[nl + 1];
    const int* cl = col + s * ESUB;
    const float* dv = dinv + s * NSUB;
    float4 acc = {0.f, 0.f, 0.f, 0.f};
    for (int p = st; p < en; p++) {
        int src = cl[p];
        float d = dv[src];
        float4 hv = h[((size_t)(s * NSUB + src)) * 32 + f4];
        acc.x += hv.x * d; acc.y += hv.y * d; acc.z += hv.z * d; acc.w += hv.w * d;
    }
    size_t node = (size_t)s * NSUB + nl;
    float dn = dv[nl];
    float dn2 = dn * dn;
    float4 hs = h[node * 32 + f4];
    float4 bb = ((const float4*)bias)[f4];
    float4 r;
    r.x = fmaxf(acc.x * dn + hs.x * dn2 + bb.x, 0.f);
    r.y = fmaxf(acc.y * dn + hs.y * dn2 + bb.y, 0.f);
    r.z = fmaxf(acc.z * dn + hs.z * dn2 + bb.z, 0.f);
    r.w = fmaxf(acc.w * dn + hs.w * dn2 + bb.w, 0.f);
    size_t orow = SCATTER ? (size_t)posR[node] : node;
    out[orow * 32 + f4] = r;
    if (SCORE) {
        float4 wp = ((const float4*)Wp)[f4];
        float p = r.x * wp.x + r.y * wp.y + r.z * wp.z + r.w * wp.w;
        #pragma unroll
        for (int o = 16; o > 0; o >>= 1) p += __shfl_xor(p, o, 32);
        if (f4 == 0) scoreh[node] = p;
    }
}

// ---------------- per-subgraph top-K (bitonic; set-invariant downstream) -----
__global__ __launch_bounds__(512) void k_topk(const float* __restrict__ score,
        int* __restrict__ perm, float* __restrict__ gate, int* __restrict__ posmap) {
    __shared__ float sv[1024];
    __shared__ int   si[1024];
    int s = blockIdx.x, t = threadIdx.x;
    for (int i = t; i < 1024; i += 512) {
        sv[i] = score[s * NSUB + i];
        si[i] = i;
        posmap[s * NSUB + i] = -1;
    }
    __syncthreads();
    for (int k = 2; k <= 1024; k <<= 1) {
        for (int j = k >> 1; j > 0; j >>= 1) {
            for (int b = t; b < 1024; b += 512) {
                int ixj = b ^ j;
                if (ixj > b) {
                    bool desc = ((b & k) == 0);
                    bool sw = desc ? (sv[b] < sv[ixj]) : (sv[b] > sv[ixj]);
                    if (sw) {
                        float tv = sv[b]; sv[b] = sv[ixj]; sv[ixj] = tv;
                        int ti = si[b]; si[b] = si[ixj]; si[ixj] = ti;
                    }
                }
            }
            __syncthreads();
        }
    }
    if (t < KSEL) {
        perm[s * KSEL + t] = si[t];
        gate[s * KSEL + t] = tanhf(sv[t]);
        posmap[s * NSUB + si[t]] = t;
    }
}

// fused deg2 + xpool
__global__ __launch_bounds__(256) void k_pool(const float4* __restrict__ x1,
        const int* __restrict__ perm, const float* __restrict__ gate,
        const int* __restrict__ posmap, const int* __restrict__ rowptr,
        const int* __restrict__ col, float* __restrict__ dinv2,
        float4* __restrict__ xpool) {
    int t = threadIdx.x;
    int i = blockIdx.x * 8 + (t >> 5);
    int lane = t & 31;
    int s = i >> 9;
    int n = perm[i];
    const int* rp = rowptr + s * (NSUB + 1);
    const int* cl = col + s * ESUB;
    int st = rp[n], en = rp[n + 1];
    int c = 0;
    for (int p = st + lane; p < en; p += 32) c += (posmap[s * NSUB + cl[p]] >= 0) ? 1 : 0;
    #pragma unroll
    for (int o = 16; o > 0; o >>= 1) c += __shfl_xor(c, o, 32);
    if (lane == 0) dinv2[i] = rsqrtf((float)(c + 1));
    float g = gate[i];
    float4 v = x1[((size_t)(s * NSUB + n)) * 32 + lane];
    v.x *= g; v.y *= g; v.z *= g; v.w *= g;
    xpool[(size_t)i * 32 + lane] = v;
}

// max/mean over 512 rows -> [256] per subgraph
__global__ __launch_bounds__(1024) void k_emb(const float* __restrict__ X,
        float* __restrict__ out) {
    __shared__ float red[4][256];
    int s = blockIdx.x, t = threadIdx.x;
    int sl = t >> 8, f = t & 255;
    const float* base = X + (size_t)s * KSEL * NH;
    float r;
    if (f < NH) {
        r = -INFINITY;
        for (int i = sl * 128; i < sl * 128 + 128; i++) r = fmaxf(r, base[i * NH + f]);
    } else {
        r = 0.f;
        for (int i = sl * 128; i < sl * 128 + 128; i++) r += base[i * NH + (f - NH)];
    }
    red[sl][f] = r;
    __syncthreads();
    if (sl == 0) {
        float a = red[0][f], b = red[1][f], c = red[2][f], d = red[3][f];
        float v = (f < NH) ? fmaxf(fmaxf(a, b), fmaxf(c, d)) : (a + b + c + d) * (1.f / KSEL);
        out[s * 256 + f] = v;
    }
}

// ---- fused: blocks [0,4096) pooled GCN aggregate; [4096,4224) binN ----------
__global__ __launch_bounds__(256) void k_aggp_bin(const float4* __restrict__ hp,
        const float* __restrict__ dinv2, const int* __restrict__ perm,
        const int* __restrict__ posmap, const int* __restrict__ rowptr,
        const int* __restrict__ col, const float* __restrict__ bsc,
        float4* __restrict__ xsub,
        const int* __restrict__ gei, int* __restrict__ bcur, int* __restrict__ ebin) {
    int t = threadIdx.x;
    if (blockIdx.x >= 4096) {                        // binN (count-based bcur, memset-0)
        __shared__ int lh[64];
        __shared__ int lbase[64];
        if (t < 64) lh[t] = 0;
        __syncthreads();
        int e0 = (blockIdx.x - 4096) * 8192;
        #pragma unroll 8
        for (int k = 0; k < 32; k++) {
            int d = gei[EG + e0 + k * 256 + t];
            atomicAdd(&lh[d >> 10], 1);
        }
        __syncthreads();
        if (t < 64) {
            lbase[t] = t * BCAP + atomicAdd(&bcur[t], lh[t]);
            lh[t] = 0;
        }
        __syncthreads();
        #pragma unroll 4
        for (int k = 0; k < 32; k++) {
            int idx = e0 + k * 256 + t;
            int d = gei[EG + idx];
            int src = gei[idx];
            int bb = d >> 10;
            int pos = lbase[bb] + atomicAdd(&lh[bb], 1);
            ebin[pos] = src | ((d & 1023) << 16);
        }
        return;
    }
    int b = blockIdx.x;
    int s = b & 63;
    int chunk = b >> 6;
    int il = chunk * 8 + (t >> 5);
    int f4 = t & 31;
    int i = s * KSEL + il;
    int n = perm[i];
    const int* rp = rowptr + s * (NSUB + 1);
    const int* cl = col + s * ESUB;
    int st = rp[n], en = rp[n + 1];
    float4 acc = {0.f, 0.f, 0.f, 0.f};
    for (int p = st; p < en; p++) {
        int j = posmap[s * NSUB + cl[p]];
        if (j >= 0) {
            float d = dinv2[s * KSEL + j];
            float4 hv = hp[((size_t)(s * KSEL + j)) * 32 + f4];
            acc.x += hv.x * d; acc.y += hv.y * d; acc.z += hv.z * d; acc.w += hv.w * d;
        }
    }
    float dn = dinv2[i];
    float dn2 = dn * dn;
    float4 hs = hp[(size_t)i * 32 + f4];
    float4 bb = ((const float4*)bsc)[f4];
    float4 r;
    r.x = fmaxf(acc.x * dn + hs.x * dn2 + bb.x, 0.f);
    r.y = fmaxf(acc.y * dn + hs.y * dn2 + bb.y, 0.f);
    r.z = fmaxf(acc.z * dn + hs.z * dn2 + bb.z, 0.f);
    r.w = fmaxf(acc.w * dn + hs.w * dn2 + bb.w, 0.f);
    xsub[(size_t)i * 32 + f4] = r;
}

// ---- fused: blocks [0,64) emb_attn (pass2 + attention + AW); [64,128) fillB3 ----
__global__ __launch_bounds__(1024) void k_ea_fb(const float* __restrict__ X,
        const float* __restrict__ subemb, const float* __restrict__ Wqkv,
        const float* __restrict__ bqkv, const float* __restrict__ Wo,
        const float* __restrict__ bo, const float* __restrict__ Wf,
        float* __restrict__ att, float* __restrict__ AW,
        const int* __restrict__ ebin, const int* __restrict__ bcur,
        int* __restrict__ rowptrN, float* __restrict__ dinvN, int* __restrict__ colN) {
    int t = threadIdx.x;
    if (blockIdx.x >= 64) {
        // fillB3: one block per bucket -> LDS hist/scan -> rowptrN/dinvN + cursor fill
        __shared__ int sh2[1024];
        __shared__ int curL[1024];
        __shared__ int sbase;
        int b = blockIdx.x - 64;
        if (t == 0) {
            int run = 0;
            for (int i = 0; i < b; i++) run += bcur[i];
            sbase = run;
        }
        curL[t] = 0;
        __syncthreads();
        int st = b * BCAP, en = st + bcur[b];
        for (int i = st + t; i < en; i += 1024) atomicAdd(&curL[ebin[i] >> 16], 1);
        __syncthreads();
        int v = curL[t];
        sh2[t] = v;
        __syncthreads();
        for (int off = 1; off < 1024; off <<= 1) {
            int add = (t >= off) ? sh2[t - off] : 0;
            __syncthreads();
            sh2[t] += add;
            __syncthreads();
        }
        int incl = sh2[t];
        int excl = incl - v;
        int base = sbase;
        rowptrN[(b << 10) + t] = base + excl;
        dinvN[(b << 10) + t] = rsqrtf((float)(v + 1));
        if (b == 63 && t == 1023) rowptrN[NG] = base + incl;   // = EG
        curL[t] = base + excl;
        __syncthreads();
        for (int i = st + t; i < en; i += 1024) {
            int packed = ebin[i];
            int p = atomicAdd(&curL[packed >> 16], 1);
            colN[p] = packed & 0xFFFF;
        }
        return;
    }
    __shared__ float red[4][256];
    __shared__ float se[256], t1[256], av[256];
    int s = blockIdx.x;
    int sl = t >> 8, f = t & 255;
    const float* base = X + (size_t)s * KSEL * NH;
    float r;
    if (f < NH) {
        r = -INFINITY;
        for (int i = sl * 128; i < sl * 128 + 128; i++) r = fmaxf(r, base[i * NH + f]);
    } else {
        r = 0.f;
        for (int i = sl * 128; i < sl * 128 + 128; i++) r += base[i * NH + (f - NH)];
    }
    red[sl][f] = r;
    __syncthreads();
    if (sl == 0) {
        float a = red[0][f], b = red[1][f], c = red[2][f], d = red[3][f];
        float v = (f < NH) ? fmaxf(fmaxf(a, b), fmaxf(c, d)) : (a + b + c + d) * (1.f / KSEL);
        se[f] = subemb[s * 256 + f] + v;
    }
    __syncthreads();
    if (sl == 0) {
        float acc = bqkv[512 + f];
        for (int k = 0; k < 256; k++) acc += se[k] * Wqkv[(size_t)k * 768 + 512 + f];
        t1[f] = acc;
    }
    __syncthreads();
    if (sl == 0) {
        float a2 = bo[f];
        for (int k = 0; k < 256; k++) a2 += t1[k] * Wo[(size_t)k * 256 + f];
        att[s * 256 + f] = a2;
        av[f] = a2;
    }
    __syncthreads();
    if (sl == 0 && f < 64) {
        float acc = 0.f;
        for (int k = 0; k < 256; k++) acc += av[k] * Wf[(size_t)(NH + k) * 64 + f];
        AW[s * 64 + f] = acc;
    }
}

// ---- fused: blocks [0,NG/8) streaming gather (8 nodes/blk, 32 lanes each);
//      blocks [NG/8, NG/8+NG/64) X2Ws matmul (+AW epilogue) ------------------
__global__ __launch_bounds__(256) void k_gx(const float4* __restrict__ x2s,
        const float4* __restrict__ att, const int* __restrict__ rowptrR,
        const int* __restrict__ rowlist, float4* __restrict__ gemb,
        const float* __restrict__ X, const float* __restrict__ W,
        const float* __restrict__ AW, float* __restrict__ Y) {
    int t = threadIdx.x;
    if (blockIdx.x < NG / 8) {
        int g = blockIdx.x * 8 + (t >> 5);
        int lane = t & 31;
        int st = rowptrR[g], en = rowptrR[g + 1];
        float4 a0 = {0.f,0.f,0.f,0.f}, a1 = {0.f,0.f,0.f,0.f}, a2 = {0.f,0.f,0.f,0.f};
        for (int p = st; p < en; p++) {
            float4 v = x2s[(size_t)p * 32 + lane];
            a0.x += v.x; a0.y += v.y; a0.z += v.z; a0.w += v.w;
            int sub = rowlist[p] >> 10;
            float4 w1 = att[(size_t)sub * 64 + lane];
            float4 w2 = att[(size_t)sub * 64 + 32 + lane];
            a1.x += w1.x; a1.y += w1.y; a1.z += w1.z; a1.w += w1.w;
            a2.x += w2.x; a2.y += w2.y; a2.z += w2.z; a2.w += w2.w;
        }
        gemb[(size_t)g * 96 + lane]      = a0;
        gemb[(size_t)g * 96 + 32 + lane] = a1;
        gemb[(size_t)g * 96 + 64 + lane] = a2;
        return;
    }
    __shared__ float As[16][72];
    __shared__ float Bs[16][72];
    int row0 = (blockIdx.x - NG / 8) * 64;
    int tr = t >> 4, tc = t & 15;
    float acc[4][4] = {};
    for (int k0 = 0; k0 < 128; k0 += 16) {
        {   int r = t >> 2, kq = t & 3;
            float4 v = *(const float4*)&X[(size_t)(row0 + r) * 128 + k0 + kq * 4];
            As[kq * 4 + 0][r] = v.x; As[kq * 4 + 1][r] = v.y;
            As[kq * 4 + 2][r] = v.z; As[kq * 4 + 3][r] = v.w;
        }
        {   int k = t >> 4, cq = t & 15;
            float4 v = *(const float4*)&W[(size_t)(k0 + k) * 64 + cq * 4];
            *(float4*)&Bs[k][cq * 4] = v;
        }
        __syncthreads();
        #pragma unroll
        for (int k = 0; k < 16; k++) {
            float a0 = As[k][tr * 4 + 0], a1 = As[k][tr * 4 + 1];
            float a2 = As[k][tr * 4 + 2], a3 = As[k][tr * 4 + 3];
            float b0 = Bs[k][tc * 4 + 0], b1 = Bs[k][tc * 4 + 1];
            float b2 = Bs[k][tc * 4 + 2], b3 = Bs[k][tc * 4 + 3];
            acc[0][0] += a0 * b0; acc[0][1] += a0 * b1; acc[0][2] += a0 * b2; acc[0][3] += a0 * b3;
            acc[1][0] += a1 * b0; acc[1][1] += a1 * b1; acc[1][2] += a1 * b2; acc[1][3] += a1 * b3;
            acc[2][0] += a2 * b0; acc[2][1] += a2 * b1; acc[2][2] += a2 * b2; acc[2][3] += a2 * b3;
            acc[3][0] += a3 * b0; acc[3][1] += a3 * b1; acc[3][2] += a3 * b2; acc[3][3] += a3 * b3;
        }
        __syncthreads();
    }
    #pragma unroll
    for (int i = 0; i < 4; i++) {
        int rr = row0 + tr * 4 + i;
        int sub = rowlist[rr] >> 10;
        const float4 aw = *(const float4*)&AW[(size_t)sub * 64 + tc * 4];
        float4 v = { acc[i][0] + aw.x, acc[i][1] + aw.y, acc[i][2] + aw.z, acc[i][3] + aw.w };
        *(float4*)&Y[(size_t)rr * 64 + tc * 4] = v;
    }
}

// hf[g] = sum_p X2Ws[p]  -- pure streaming segmented sum
__global__ __launch_bounds__(256) void k_gatherH(const float4* __restrict__ X2Ws,
        const int* __restrict__ rowptrR, float4* __restrict__ hf) {
    int t = threadIdx.x;
    int g = blockIdx.x * 16 + (t >> 4);
    int f4 = t & 15;
    int st = rowptrR[g], en = rowptrR[g + 1];
    float4 acc = {0.f, 0.f, 0.f, 0.f};
    for (int p = st; p < en; p++) {
        float4 a = X2Ws[(size_t)p * 16 + f4];
        acc.x += a.x; acc.y += a.y; acc.z += a.z; acc.w += a.w;
    }
    hf[(size_t)g * 16 + f4] = acc;
}

// final GCN aggregate + bias + log_softmax (64 classes = 16 float4 lanes)
__global__ __launch_bounds__(256) void k_final(const float4* __restrict__ hf,
        const float* __restrict__ dinvN, const int* __restrict__ rowptr,
        const int* __restrict__ col, const float* __restrict__ bfb,
        float4* __restrict__ out) {
    int t = threadIdx.x;
    int n = blockIdx.x * 16 + (t >> 4);
    int f4 = t & 15;
    int st = rowptr[n], en = rowptr[n + 1];
    float4 acc = {0.f, 0.f, 0.f, 0.f};
    for (int p = st; p < en; p++) {
        int src = col[p];
        float d = dinvN[src];
        float4 hv = hf[(size_t)src * 16 + f4];
        acc.x += hv.x * d; acc.y += hv.y * d; acc.z += hv.z * d; acc.w += hv.w * d;
    }
    float dn = dinvN[n];
    float dn2 = dn * dn;
    float4 hs = hf[(size_t)n * 16 + f4];
    float4 bb = ((const float4*)bfb)[f4];
    float4 x;
    x.x = acc.x * dn + hs.x * dn2 + bb.x;
    x.y = acc.y * dn + hs.y * dn2 + bb.y;
    x.z = acc.z * dn + hs.z * dn2 + bb.z;
    x.w = acc.w * dn + hs.w * dn2 + bb.w;
    float m = fmaxf(fmaxf(x.x, x.y), fmaxf(x.z, x.w));
    for (int o = 1; o < 16; o <<= 1) m = fmaxf(m, __shfl_xor(m, o, 64));
    float ssum = expf(x.x - m) + expf(x.y - m) + expf(x.z - m) + expf(x.w - m);
    for (int o = 1; o < 16; o <<= 1) ssum += __shfl_xor(ssum, o, 64);
    float lz = m + logf(ssum);
    float4 r = { x.x - lz, x.y - lz, x.z - lz, x.w - lz };
    out[(size_t)n * 16 + f4] = r;
}

// ---------------- host ----------------
extern "C" void kernel_launch(void* const* d_in, const int* in_sizes, int n_in,
                              void* d_out, int out_size, void* d_ws, size_t ws_size,
                              hipStream_t stream) {
    const float* sub_x = (const float*)d_in[0];
    const int*   sei   = (const int*)d_in[1];
    const int*   sorig = (const int*)d_in[2];
    const int*   gei   = (const int*)d_in[3];
    const float *W1 = (const float*)d_in[4],  *b1  = (const float*)d_in[5];
    const float *W2 = (const float*)d_in[6],  *b2  = (const float*)d_in[7];
    const float *Wp = (const float*)d_in[8],  *bp  = (const float*)d_in[9];
    const float *Wsc = (const float*)d_in[10], *bsc = (const float*)d_in[11];
    const float *Wqkv = (const float*)d_in[12], *bqkv = (const float*)d_in[13];
    const float *Wo = (const float*)d_in[14], *bo  = (const float*)d_in[15];
    const float *Wf = (const float*)d_in[16], *bfb = (const float*)d_in[17];

    float* out0 = (float*)d_out;                      // log-softmax [NG,64]
    float* gemb = (float*)d_out + (size_t)NG * 64;    // global_emb [NG,384] in-place

    char* w = (char*)d_ws;
    size_t off = 0;
    auto alloc = [&](size_t nbytes) -> void* {
        off = (off + 255) & ~(size_t)255;
        void* p = w + off;
        off += nbytes;
        return p;
    };
    // bcur + cntR adjacent -> single memset covers both
    int*   bcur    = (int*)alloc(64 * 4);              // counts (init 0)
    int*   cntR    = (int*)alloc((size_t)NG * 4);
    float* AW      = (float*)alloc((size_t)S * 64 * 4);
    float* dinv    = (float*)alloc((size_t)NG * 4);        // subgraph dinv; later dinvN
    float* scoreh  = (float*)alloc((size_t)NG * 4);
    float* score   = (float*)alloc((size_t)NG * 4);
    float* gate    = (float*)alloc((size_t)S * KSEL * 4);
    float* dinv2   = (float*)alloc((size_t)S * KSEL * 4);
    float* subemb  = (float*)alloc((size_t)S * 256 * 4);
    float* att     = (float*)alloc((size_t)S * 256 * 4);
    int*   perm    = (int*)alloc((size_t)S * KSEL * 4);
    int*   posmap  = (int*)alloc((size_t)NG * 4);
    int*   cur_sub = (int*)alloc((size_t)NG * 4);          // used as curR
    int*   rowptr_s= (int*)alloc((size_t)(NG + 64) * 4);   // alias: rowptrN
    int*   col_sub = (int*)alloc((size_t)EG * 4);          // alias: colN
    int*   rowptrR = (int*)alloc((size_t)(NG + 64) * 4);
    int*   rowlist = (int*)alloc((size_t)NG * 4);
    int*   posR    = (int*)alloc((size_t)NG * 4);
    float* x1      = (float*)alloc((size_t)NG * NH * 4);   // alias: xsub, later X2Ws
    float* x2s     = (float*)alloc((size_t)NG * NH * 4);   // GCN2 out, PERMUTED to rowlist order
    float* hbuf    = (float*)alloc((size_t)NG * NH * 4);   // alias: hf
    float* xpool   = (float*)alloc((size_t)S * KSEL * NH * 4);  // alias: ebin
    float* xsub    = x1;
    float* hf      = hbuf;
    float* dinvN   = dinv;
    float* X2Ws    = x1;                                   // x1 dead after k_ea_fb
    int*   curR    = cur_sub;
    int*   rowptrN = rowptr_s;
    int*   colN    = col_sub;
    int*   ebin    = (int*)xpool;                          // xpool dead after mmP (binN runs fused w/ aggP)

    hipMemsetAsync(bcur, 0, 256 + (size_t)NG * 4, stream);   // bcur + cntR in one

    // per-subgraph CSR (blocks 0-63) + countR (blocks 64-127); then inverse-row CSR
    k_csr_sub<<<128, 1024, 0, stream>>>(sei, sorig, rowptr_s, col_sub, dinv, cntR);
    k_scanR<<<64, 1024, 0, stream>>>(cntR, rowptrR, curR);
    k_fillR<<<NG / 256, 256, 0, stream>>>(sorig, curR, rowlist, posR);

    // GCN1 (+ fused scorer h = x1 @ Wp)
    k_matmul<128, 128><<<dim3(NG / 64, 2), 256, 0, stream>>>(sub_x, W1, hbuf);
    k_agg128<true, false><<<8192, 256, 0, stream>>>((const float4*)hbuf, dinv, rowptr_s,
                                                    col_sub, b1, Wp, nullptr, (float4*)x1, scoreh);
    // GCN2 matmul || score_agg (independent, both depend only on agg1 outputs)
    k_mm2s<<<2048 + NG / 256, 256, 0, stream>>>(x1, W2, hbuf,
                                                scoreh, dinv, rowptr_s, col_sub, bp, score);
    // GCN2 aggregate -> x2s written in rowlist order
    k_agg128<false, true><<<8192, 256, 0, stream>>>((const float4*)hbuf, dinv, rowptr_s,
                                                    col_sub, b2, nullptr, posR, (float4*)x2s, nullptr);
    // top-k pooling
    k_topk<<<S, 512, 0, stream>>>(score, perm, gate, posmap);
    k_pool<<<(S * KSEL) / 8, 256, 0, stream>>>((const float4*)x1, perm, gate, posmap,
                                               rowptr_s, col_sub, dinv2, (float4*)xpool);
    k_emb<<<S, 1024, 0, stream>>>(xpool, subemb);
    // pooled GCN matmul (last reader of xpool before ebin alias takes over)
    k_matmul<128, 128><<<dim3((S * KSEL) / 64, 2), 256, 0, stream>>>(xpool, Wsc, hbuf);
    // pooled aggregate || binN (binN only needs gei+bcur; ebin=xpool alias now safe)
    k_aggp_bin<<<4096 + EG / 8192, 256, 0, stream>>>((const float4*)hbuf, dinv2, perm, posmap,
                                                     rowptr_s, col_sub, bsc, (float4*)xsub,
                                                     gei, bcur, ebin);
    // emb pass2 + attention + AW || fillB3 (rowptrN/colN/dinvN free of readers here)
    k_ea_fb<<<128, 1024, 0, stream>>>(xsub, subemb, Wqkv, bqkv, Wo, bo, Wf, att, AW,
                                      ebin, bcur, rowptrN, dinvN, colN);
    // streaming gather of gemb || X2Ws matmul (+AW fold)
    k_gx<<<NG / 8 + NG / 64, 256, 0, stream>>>((const float4*)x2s, (const float4*)att,
                                               rowptrR, rowlist, (float4*)gemb,
                                               x2s, Wf, AW, X2Ws);
    k_gatherH<<<NG / 16, 256, 0, stream>>>((const float4*)X2Ws, rowptrR, (float4*)hf);

    // final GCN + log_softmax
    k_final<<<NG / 16, 256, 0, stream>>>((const float4*)hf, dinvN, rowptrN, colN, bfb, (float4*)out0);

    (void)in_sizes; (void)n_in; (void)out_size; (void)ws_size;
}

// Round 8
// 663.590 us; speedup vs baseline: 1.1172x; 1.0279x over previous
//
#include <hip/hip_runtime.h>
#include <math.h>

#define S     64
#define NSUB  1024
#define ESUB  16384
#define NG    65536
#define EG    1048576
#define NH    128
#define KSEL  512
#define BCAP  20480   // per-bucket ebin capacity; bucket ~ Binom(1M,1/64): mean 16384, sd 127

// ---- 1024-thread 128x128-tile matmul (KDIM=NCOL=128). k ascends exactly like the
// 64x64 256-thr version -> bitwise-identical per-element accumulation order.
__device__ __forceinline__ void mm1024_tile(const float* __restrict__ X,
        const float* __restrict__ W, float* __restrict__ Y, int row0, int t,
        float (*As)[136], float (*Bs)[136]) {
    int tr = t >> 5, tc = t & 31;
    float acc[4][4] = {};
    for (int k0 = 0; k0 < 128; k0 += 16) {
        if (t < 512) {                               // stage A: 128 rows x 16 k
            int r = t >> 2, kq = t & 3;
            float4 v = *(const float4*)&X[(size_t)(row0 + r) * 128 + k0 + kq * 4];
            As[kq * 4 + 0][r] = v.x; As[kq * 4 + 1][r] = v.y;
            As[kq * 4 + 2][r] = v.z; As[kq * 4 + 3][r] = v.w;
        } else {                                     // stage B: 16 k x 128 cols
            int u = t - 512;
            int k = u >> 5, c = (u & 31) * 4;
            *(float4*)&Bs[k][c] = *(const float4*)&W[(size_t)(k0 + k) * 128 + c];
        }
        __syncthreads();
        #pragma unroll
        for (int k = 0; k < 16; k++) {
            float a0 = As[k][tr * 4 + 0], a1 = As[k][tr * 4 + 1];
            float a2 = As[k][tr * 4 + 2], a3 = As[k][tr * 4 + 3];
            float b0 = Bs[k][tc * 4 + 0], b1 = Bs[k][tc * 4 + 1];
            float b2 = Bs[k][tc * 4 + 2], b3 = Bs[k][tc * 4 + 3];
            acc[0][0] += a0 * b0; acc[0][1] += a0 * b1; acc[0][2] += a0 * b2; acc[0][3] += a0 * b3;
            acc[1][0] += a1 * b0; acc[1][1] += a1 * b1; acc[1][2] += a1 * b2; acc[1][3] += a1 * b3;
            acc[2][0] += a2 * b0; acc[2][1] += a2 * b1; acc[2][2] += a2 * b2; acc[2][3] += a2 * b3;
            acc[3][0] += a3 * b0; acc[3][1] += a3 * b1; acc[3][2] += a3 * b2; acc[3][3] += a3 * b3;
        }
        __syncthreads();
    }
    #pragma unroll
    for (int i = 0; i < 4; i++) {
        float4 v = { acc[i][0], acc[i][1], acc[i][2], acc[i][3] };
        *(float4*)&Y[(size_t)(row0 + tr * 4 + i) * 128 + tc * 4] = v;
    }
}

// ---- fused: blocks [0,64) per-subgraph CSR; [64,128) countR; [128,384) mm1 tiles 0-255
__global__ __launch_bounds__(1024) void k_csr_mm1(const int* __restrict__ sei,
        const int* __restrict__ sorig, int* __restrict__ rowptr, int* __restrict__ col,
        float* __restrict__ dinv, int* __restrict__ cntR,
        const float* __restrict__ X, const float* __restrict__ W, float* __restrict__ Y) {
    __shared__ float As[16][136];
    __shared__ float Bs[16][136];
    __shared__ int sh[1024];
    __shared__ int curL[1024];
    int b = blockIdx.x, t = threadIdx.x;
    if (b >= 128) {                                  // mm1 first half (rows 0..32767)
        mm1024_tile(X, W, Y, (b - 128) * 128, t, As, Bs);
        return;
    }
    if (b >= 64) {                                   // folded countR (NG entries)
        int r = (b - 64) * 1024 + t;
        atomicAdd(&cntR[sorig[r]], 1);
        return;
    }
    int s = b;
    curL[t] = 0;
    __syncthreads();
    const int* dstp = sei + s * 2 * ESUB + ESUB;
    #pragma unroll
    for (int k = 0; k < 16; k++) atomicAdd(&curL[dstp[k * 1024 + t]], 1);
    __syncthreads();
    int v = curL[t];
    sh[t] = v;
    __syncthreads();
    for (int off = 1; off < 1024; off <<= 1) {
        int add = (t >= off) ? sh[t - off] : 0;
        __syncthreads();
        sh[t] += add;
        __syncthreads();
    }
    int incl = sh[t];
    int excl = incl - v;
    rowptr[s * (NSUB + 1) + t] = excl;
    dinv[s * NSUB + t] = rsqrtf((float)(v + 1));     // deg = indeg + 1 (self loop)
    if (t == 1023) rowptr[s * (NSUB + 1) + NSUB] = incl;
    curL[t] = s * ESUB + excl;                       // absolute cursor
    __syncthreads();
    const int* srcp = sei + s * 2 * ESUB;
    #pragma unroll
    for (int k = 0; k < 16; k++) {
        int e = k * 1024 + t;
        int src = srcp[e];
        int dst = dstp[e];
        int p = atomicAdd(&curL[dst], 1);
        col[p] = src;
    }
}

// ---- fused: blocks [0,64) scanR (p1+p3); [64,320) mm1 tiles 256-511 ----------
__global__ __launch_bounds__(1024) void k_scan_mm1(const int* __restrict__ cnt,
        int* __restrict__ rowptr, int* __restrict__ cur,
        const float* __restrict__ X, const float* __restrict__ W, float* __restrict__ Y) {
    __shared__ float As[16][136];
    __shared__ float Bs[16][136];
    __shared__ int sh[1024];
    __shared__ int wsum[16];
    __shared__ int sboff;
    int b = blockIdx.x, t = threadIdx.x;
    if (b >= 64) {                                   // mm1 second half (rows 32768..65535)
        mm1024_tile(X, W, Y, (b - 64 + 256) * 128, t, As, Bs);
        return;
    }
    int pre = 0;
    for (int i = t; i < b * 1024; i += 1024) pre += cnt[i];
    #pragma unroll
    for (int o = 32; o > 0; o >>= 1) pre += __shfl_xor(pre, o, 64);
    if ((t & 63) == 0) wsum[t >> 6] = pre;
    __syncthreads();
    if (t == 0) {
        int r = 0;
        #pragma unroll
        for (int i = 0; i < 16; i++) r += wsum[i];
        sboff = r;
    }
    int v = cnt[b * 1024 + t];
    sh[t] = v;
    __syncthreads();
    for (int off = 1; off < 1024; off <<= 1) {
        int add = (t >= off) ? sh[t - off] : 0;
        __syncthreads();
        sh[t] += add;
        __syncthreads();
    }
    int base = sboff;
    int r = base + sh[t] - v;
    int idx = b * 1024 + t;
    rowptr[idx] = r;
    cur[idx] = r;
    if (b == 63 && t == 1023) rowptr[NG] = base + sh[t];   // = NG
}

// fillR: rowlist (pos->row) AND posR (row->pos) for producer-side permutation
__global__ void k_fillR(const int* __restrict__ orig, int* __restrict__ cur,
                        int* __restrict__ rowlist, int* __restrict__ posR) {
    int r = blockIdx.x * 256 + threadIdx.x;          // < NG
    int p = atomicAdd(&cur[orig[r]], 1);
    rowlist[p] = r;
    posR[r] = p;
}

// ---- fused: blocks [0,2048) matmul2 (64x64 tiles, flattened); [2048,2304) score_agg ----
__global__ __launch_bounds__(256) void k_mm2s(const float* __restrict__ X,
        const float* __restrict__ W, float* __restrict__ Y,
        const float* __restrict__ sh, const float* __restrict__ dinv,
        const int* __restrict__ rowptr, const int* __restrict__ col,
        const float* __restrict__ bp, float* __restrict__ score) {
    int t = threadIdx.x;
    if (blockIdx.x >= 2048) {                        // score_agg
        int n = (blockIdx.x - 2048) * 256 + t;
        int s = n >> 10, nl = n & (NSUB - 1);
        const int* rp = rowptr + s * (NSUB + 1);
        const int* cl = col + s * ESUB;
        const float* dv = dinv + s * NSUB;
        int st = rp[nl], en = rp[nl + 1];
        float acc = 0.f;
        for (int p = st; p < en; p++) {
            int src = cl[p];
            acc += sh[s * NSUB + src] * dv[src];
        }
        float dn = dv[nl];
        score[n] = acc * dn + sh[n] * dn * dn + bp[0];
        return;
    }
    __shared__ float As[16][72];
    __shared__ float Bs[16][72];
    int row0 = (blockIdx.x & 1023) * 64;
    int col0 = (blockIdx.x >> 10) * 64;
    int tr = t >> 4, tc = t & 15;
    float acc[4][4] = {};
    for (int k0 = 0; k0 < 128; k0 += 16) {
        {   int r = t >> 2, kq = t & 3;
            float4 v = *(const float4*)&X[(size_t)(row0 + r) * 128 + k0 + kq * 4];
            As[kq * 4 + 0][r] = v.x; As[kq * 4 + 1][r] = v.y;
            As[kq * 4 + 2][r] = v.z; As[kq * 4 + 3][r] = v.w;
        }
        {   int k = t >> 4, cq = t & 15;
            float4 v = *(const float4*)&W[(size_t)(k0 + k) * 128 + col0 + cq * 4];
            *(float4*)&Bs[k][cq * 4] = v;
        }
        __syncthreads();
        #pragma unroll
        for (int k = 0; k < 16; k++) {
            float a0 = As[k][tr * 4 + 0], a1 = As[k][tr * 4 + 1];
            float a2 = As[k][tr * 4 + 2], a3 = As[k][tr * 4 + 3];
            float b0 = Bs[k][tc * 4 + 0], b1 = Bs[k][tc * 4 + 1];
            float b2 = Bs[k][tc * 4 + 2], b3 = Bs[k][tc * 4 + 3];
            acc[0][0] += a0 * b0; acc[0][1] += a0 * b1; acc[0][2] += a0 * b2; acc[0][3] += a0 * b3;
            acc[1][0] += a1 * b0; acc[1][1] += a1 * b1; acc[1][2] += a1 * b2; acc[1][3] += a1 * b3;
            acc[2][0] += a2 * b0; acc[2][1] += a2 * b1; acc[2][2] += a2 * b2; acc[2][3] += a2 * b3;
            acc[3][0] += a3 * b0; acc[3][1] += a3 * b1; acc[3][2] += a3 * b2; acc[3][3] += a3 * b3;
        }
        __syncthreads();
    }
    #pragma unroll
    for (int i = 0; i < 4; i++) {
        float4 v = { acc[i][0], acc[i][1], acc[i][2], acc[i][3] };
        *(float4*)&Y[(size_t)(row0 + tr * 4 + i) * 128 + col0 + tc * 4] = v;
    }
}

// ------- GCN aggregate 1 (+ fused scorer); 256-thr, 8 nodes/block ---------------
__global__ __launch_bounds__(256) void k_agg1(const float4* __restrict__ h,
        const float* __restrict__ dinv, const int* __restrict__ rowptr,
        const int* __restrict__ col, const float* __restrict__ bias,
        const float* __restrict__ Wp, float4* __restrict__ out,
        float* __restrict__ scoreh) {
    int b = blockIdx.x;
    int s = b & 63;                      // subgraph -> fixed XCD (b%8 == s%8)
    int chunk = b >> 6;
    int t = threadIdx.x;
    int nl = chunk * 8 + (t >> 5);
    int f4 = t & 31;
    const int* rp = rowptr + s * (NSUB + 1);
    int st = rp[nl], en = rp[nl + 1];
    const int* cl = col + s * ESUB;
    const float* dv = dinv + s * NSUB;
    float4 acc = {0.f, 0.f, 0.f, 0.f};
    for (int p = st; p < en; p++) {
        int src = cl[p];
        float d = dv[src];
        float4 hv = h[((size_t)(s * NSUB + src)) * 32 + f4];
        acc.x += hv.x * d; acc.y += hv.y * d; acc.z += hv.z * d; acc.w += hv.w * d;
    }
    size_t node = (size_t)s * NSUB + nl;
    float dn = dv[nl];
    float dn2 = dn * dn;
    float4 hs = h[node * 32 + f4];
    float4 bb = ((const float4*)bias)[f4];
    float4 r;
    r.x = fmaxf(acc.x * dn + hs.x * dn2 + bb.x, 0.f);
    r.y = fmaxf(acc.y * dn + hs.y * dn2 + bb.y, 0.f);
    r.z = fmaxf(acc.z * dn + hs.z * dn2 + bb.z, 0.f);
    r.w = fmaxf(acc.w * dn + hs.w * dn2 + bb.w, 0.f);
    out[node * 32 + f4] = r;
    float4 wp = ((const float4*)Wp)[f4];
    float p = r.x * wp.x + r.y * wp.y + r.z * wp.z + r.w * wp.w;
    #pragma unroll
    for (int o = 16; o > 0; o >>= 1) p += __shfl_xor(p, o, 32);
    if (f4 == 0) scoreh[node] = p;
}

// ---- fused: blocks [0,4096) agg2 (512-thr, 16 nodes/blk, scatter to rowlist order);
//      blocks [4096,4160) top-K bitonic -------------------------------------------
__global__ __launch_bounds__(512) void k_agg2_topk(const float4* __restrict__ h,
        const float* __restrict__ dinv, const int* __restrict__ rowptr,
        const int* __restrict__ col, const float* __restrict__ bias,
        const int* __restrict__ posR, float4* __restrict__ out,
        const float* __restrict__ score, int* __restrict__ perm,
        float* __restrict__ gate, int* __restrict__ posmap) {
    int t = threadIdx.x;
    if (blockIdx.x >= 4096) {                        // topk
        __shared__ float sv[1024];
        __shared__ int   si[1024];
        int s = blockIdx.x - 4096;
        for (int i = t; i < 1024; i += 512) {
            sv[i] = score[s * NSUB + i];
            si[i] = i;
            posmap[s * NSUB + i] = -1;
        }
        __syncthreads();
        for (int k = 2; k <= 1024; k <<= 1) {
            for (int j = k >> 1; j > 0; j >>= 1) {
                for (int b = t; b < 1024; b += 512) {
                    int ixj = b ^ j;
                    if (ixj > b) {
                        bool desc = ((b & k) == 0);
                        bool sw = desc ? (sv[b] < sv[ixj]) : (sv[b] > sv[ixj]);
                        if (sw) {
                            float tv = sv[b]; sv[b] = sv[ixj]; sv[ixj] = tv;
                            int ti = si[b]; si[b] = si[ixj]; si[ixj] = ti;
                        }
                    }
                }
                __syncthreads();
            }
        }
        if (t < KSEL) {
            perm[s * KSEL + t] = si[t];
            gate[s * KSEL + t] = tanhf(sv[t]);
            posmap[s * NSUB + si[t]] = t;
        }
        return;
    }
    int b = blockIdx.x;
    int s = b & 63;
    int chunk = b >> 6;                              // 0..63
    int nl = chunk * 16 + (t >> 5);
    int f4 = t & 31;
    const int* rp = rowptr + s * (NSUB + 1);
    int st = rp[nl], en = rp[nl + 1];
    const int* cl = col + s * ESUB;
    const float* dv = dinv + s * NSUB;
    float4 acc = {0.f, 0.f, 0.f, 0.f};
    for (int p = st; p < en; p++) {
        int src = cl[p];
        float d = dv[src];
        float4 hv = h[((size_t)(s * NSUB + src)) * 32 + f4];
        acc.x += hv.x * d; acc.y += hv.y * d; acc.z += hv.z * d; acc.w += hv.w * d;
    }
    size_t node = (size_t)s * NSUB + nl;
    float dn = dv[nl];
    float dn2 = dn * dn;
    float4 hs = h[node * 32 + f4];
    float4 bb = ((const float4*)bias)[f4];
    float4 r;
    r.x = fmaxf(acc.x * dn + hs.x * dn2 + bb.x, 0.f);
    r.y = fmaxf(acc.y * dn + hs.y * dn2 + bb.y, 0.f);
    r.z = fmaxf(acc.z * dn + hs.z * dn2 + bb.z, 0.f);
    r.w = fmaxf(acc.w * dn + hs.w * dn2 + bb.w, 0.f);
    out[(size_t)posR[node] * 32 + f4] = r;           // rowlist-order scatter write
}

// fused deg2 + xpool
__global__ __launch_bounds__(256) void k_pool(const float4* __restrict__ x1,
        const int* __restrict__ perm, const float* __restrict__ gate,
        const int* __restrict__ posmap, const int* __restrict__ rowptr,
        const int* __restrict__ col, float* __restrict__ dinv2,
        float4* __restrict__ xpool) {
    int t = threadIdx.x;
    int i = blockIdx.x * 8 + (t >> 5);
    int lane = t & 31;
    int s = i >> 9;
    int n = perm[i];
    const int* rp = rowptr + s * (NSUB + 1);
    const int* cl = col + s * ESUB;
    int st = rp[n], en = rp[n + 1];
    int c = 0;
    for (int p = st + lane; p < en; p += 32) c += (posmap[s * NSUB + cl[p]] >= 0) ? 1 : 0;
    #pragma unroll
    for (int o = 16; o > 0; o >>= 1) c += __shfl_xor(c, o, 32);
    if (lane == 0) dinv2[i] = rsqrtf((float)(c + 1));
    float g = gate[i];
    float4 v = x1[((size_t)(s * NSUB + n)) * 32 + lane];
    v.x *= g; v.y *= g; v.z *= g; v.w *= g;
    xpool[(size_t)i * 32 + lane] = v;
}

// ---- fused: blocks [0,64) emb pass 1; [64,320) mmP (xpool @ Wsc, 128-tiles) ----
__global__ __launch_bounds__(1024) void k_emb_mmP(const float* __restrict__ X,
        float* __restrict__ out, const float* __restrict__ W, float* __restrict__ Y) {
    __shared__ float As[16][136];
    __shared__ float Bs[16][136];
    __shared__ float red[4][256];
    int b = blockIdx.x, t = threadIdx.x;
    if (b >= 64) {                                   // mmP: S*KSEL rows
        mm1024_tile(X, W, Y, (b - 64) * 128, t, As, Bs);
        return;
    }
    int s = b;
    int sl = t >> 8, f = t & 255;
    const float* base = X + (size_t)s * KSEL * NH;
    float r;
    if (f < NH) {
        r = -INFINITY;
        for (int i = sl * 128; i < sl * 128 + 128; i++) r = fmaxf(r, base[i * NH + f]);
    } else {
        r = 0.f;
        for (int i = sl * 128; i < sl * 128 + 128; i++) r += base[i * NH + (f - NH)];
    }
    red[sl][f] = r;
    __syncthreads();
    if (sl == 0) {
        float a = red[0][f], bb = red[1][f], c = red[2][f], d = red[3][f];
        float v = (f < NH) ? fmaxf(fmaxf(a, bb), fmaxf(c, d)) : (a + bb + c + d) * (1.f / KSEL);
        out[s * 256 + f] = v;
    }
}

// ---- fused: blocks [0,4096) pooled GCN aggregate; [4096,4224) binN ----------
__global__ __launch_bounds__(256) void k_aggp_bin(const float4* __restrict__ hp,
        const float* __restrict__ dinv2, const int* __restrict__ perm,
        const int* __restrict__ posmap, const int* __restrict__ rowptr,
        const int* __restrict__ col, const float* __restrict__ bsc,
        float4* __restrict__ xsub,
        const int* __restrict__ gei, int* __restrict__ bcur, int* __restrict__ ebin) {
    int t = threadIdx.x;
    if (blockIdx.x >= 4096) {                        // binN (count-based bcur, memset-0)
        __shared__ int lh[64];
        __shared__ int lbase[64];
        if (t < 64) lh[t] = 0;
        __syncthreads();
        int e0 = (blockIdx.x - 4096) * 8192;
        #pragma unroll 8
        for (int k = 0; k < 32; k++) {
            int d = gei[EG + e0 + k * 256 + t];
            atomicAdd(&lh[d >> 10], 1);
        }
        __syncthreads();
        if (t < 64) {
            lbase[t] = t * BCAP + atomicAdd(&bcur[t], lh[t]);
            lh[t] = 0;
        }
        __syncthreads();
        #pragma unroll 4
        for (int k = 0; k < 32; k++) {
            int idx = e0 + k * 256 + t;
            int d = gei[EG + idx];
            int src = gei[idx];
            int bb = d >> 10;
            int pos = lbase[bb] + atomicAdd(&lh[bb], 1);
            ebin[pos] = src | ((d & 1023) << 16);
        }
        return;
    }
    int b = blockIdx.x;
    int s = b & 63;
    int chunk = b >> 6;
    int il = chunk * 8 + (t >> 5);
    int f4 = t & 31;
    int i = s * KSEL + il;
    int n = perm[i];
    const int* rp = rowptr + s * (NSUB + 1);
    const int* cl = col + s * ESUB;
    int st = rp[n], en = rp[n + 1];
    float4 acc = {0.f, 0.f, 0.f, 0.f};
    for (int p = st; p < en; p++) {
        int j = posmap[s * NSUB + cl[p]];
        if (j >= 0) {
            float d = dinv2[s * KSEL + j];
            float4 hv = hp[((size_t)(s * KSEL + j)) * 32 + f4];
            acc.x += hv.x * d; acc.y += hv.y * d; acc.z += hv.z * d; acc.w += hv.w * d;
        }
    }
    float dn = dinv2[i];
    float dn2 = dn * dn;
    float4 hs = hp[(size_t)i * 32 + f4];
    float4 bb = ((const float4*)bsc)[f4];
    float4 r;
    r.x = fmaxf(acc.x * dn + hs.x * dn2 + bb.x, 0.f);
    r.y = fmaxf(acc.y * dn + hs.y * dn2 + bb.y, 0.f);
    r.z = fmaxf(acc.z * dn + hs.z * dn2 + bb.z, 0.f);
    r.w = fmaxf(acc.w * dn + hs.w * dn2 + bb.w, 0.f);
    xsub[(size_t)i * 32 + f4] = r;
}

// ---- fused: blocks [0,64) emb_attn (pass2 + attention + AW); [64,128) fillB3 ----
__global__ __launch_bounds__(1024) void k_ea_fb(const float* __restrict__ X,
        const float* __restrict__ subemb, const float* __restrict__ Wqkv,
        const float* __restrict__ bqkv, const float* __restrict__ Wo,
        const float* __restrict__ bo, const float* __restrict__ Wf,
        float* __restrict__ att, float* __restrict__ AW,
        const int* __restrict__ ebin, const int* __restrict__ bcur,
        int* __restrict__ rowptrN, float* __restrict__ dinvN, int* __restrict__ colN) {
    int t = threadIdx.x;
    if (blockIdx.x >= 64) {
        // fillB3: one block per bucket -> LDS hist/scan -> rowptrN/dinvN + cursor fill
        __shared__ int sh2[1024];
        __shared__ int curL[1024];
        __shared__ int sbase;
        int b = blockIdx.x - 64;
        if (t == 0) {
            int run = 0;
            for (int i = 0; i < b; i++) run += bcur[i];
            sbase = run;
        }
        curL[t] = 0;
        __syncthreads();
        int st = b * BCAP, en = st + bcur[b];
        for (int i = st + t; i < en; i += 1024) atomicAdd(&curL[ebin[i] >> 16], 1);
        __syncthreads();
        int v = curL[t];
        sh2[t] = v;
        __syncthreads();
        for (int off = 1; off < 1024; off <<= 1) {
            int add = (t >= off) ? sh2[t - off] : 0;
            __syncthreads();
            sh2[t] += add;
            __syncthreads();
        }
        int incl = sh2[t];
        int excl = incl - v;
        int base = sbase;
        rowptrN[(b << 10) + t] = base + excl;
        dinvN[(b << 10) + t] = rsqrtf((float)(v + 1));
        if (b == 63 && t == 1023) rowptrN[NG] = base + incl;   // = EG
        curL[t] = base + excl;
        __syncthreads();
        for (int i = st + t; i < en; i += 1024) {
            int packed = ebin[i];
            int p = atomicAdd(&curL[packed >> 16], 1);
            colN[p] = packed & 0xFFFF;
        }
        return;
    }
    __shared__ float red[4][256];
    __shared__ float se[256], t1[256], av[256];
    int s = blockIdx.x;
    int sl = t >> 8, f = t & 255;
    const float* base = X + (size_t)s * KSEL * NH;
    float r;
    if (f < NH) {
        r = -INFINITY;
        for (int i = sl * 128; i < sl * 128 + 128; i++) r = fmaxf(r, base[i * NH + f]);
    } else {
        r = 0.f;
        for (int i = sl * 128; i < sl * 128 + 128; i++) r += base[i * NH + (f - NH)];
    }
    red[sl][f] = r;
    __syncthreads();
    if (sl == 0) {
        float a = red[0][f], b = red[1][f], c = red[2][f], d = red[3][f];
        float v = (f < NH) ? fmaxf(fmaxf(a, b), fmaxf(c, d)) : (a + b + c + d) * (1.f / KSEL);
        se[f] = subemb[s * 256 + f] + v;
    }
    __syncthreads();
    if (sl == 0) {
        float acc = bqkv[512 + f];
        for (int k = 0; k < 256; k++) acc += se[k] * Wqkv[(size_t)k * 768 + 512 + f];
        t1[f] = acc;
    }
    __syncthreads();
    if (sl == 0) {
        float a2 = bo[f];
        for (int k = 0; k < 256; k++) a2 += t1[k] * Wo[(size_t)k * 256 + f];
        att[s * 256 + f] = a2;
        av[f] = a2;
    }
    __syncthreads();
    if (sl == 0 && f < 64) {
        float acc = 0.f;
        for (int k = 0; k < 256; k++) acc += av[k] * Wf[(size_t)(NH + k) * 64 + f];
        AW[s * 64 + f] = acc;
    }
}

// ---- fused: blocks [0,NG/8) streaming gather (8 nodes/blk, 32 lanes each);
//      blocks [NG/8, NG/8+NG/64) X2Ws matmul (+AW epilogue) ------------------
__global__ __launch_bounds__(256) void k_gx(const float4* __restrict__ x2s,
        const float4* __restrict__ att, const int* __restrict__ rowptrR,
        const int* __restrict__ rowlist, float4* __restrict__ gemb,
        const float* __restrict__ X, const float* __restrict__ W,
        const float* __restrict__ AW, float* __restrict__ Y) {
    int t = threadIdx.x;
    if (blockIdx.x < NG / 8) {
        int g = blockIdx.x * 8 + (t >> 5);
        int lane = t & 31;
        int st = rowptrR[g], en = rowptrR[g + 1];
        float4 a0 = {0.f,0.f,0.f,0.f}, a1 = {0.f,0.f,0.f,0.f}, a2 = {0.f,0.f,0.f,0.f};
        for (int p = st; p < en; p++) {
            float4 v = x2s[(size_t)p * 32 + lane];
            a0.x += v.x; a0.y += v.y; a0.z += v.z; a0.w += v.w;
            int sub = rowlist[p] >> 10;
            float4 w1 = att[(size_t)sub * 64 + lane];
            float4 w2 = att[(size_t)sub * 64 + 32 + lane];
            a1.x += w1.x; a1.y += w1.y; a1.z += w1.z; a1.w += w1.w;
            a2.x += w2.x; a2.y += w2.y; a2.z += w2.z; a2.w += w2.w;
        }
        gemb[(size_t)g * 96 + lane]      = a0;
        gemb[(size_t)g * 96 + 32 + lane] = a1;
        gemb[(size_t)g * 96 + 64 + lane] = a2;
        return;
    }
    __shared__ float As[16][72];
    __shared__ float Bs[16][72];
    int row0 = (blockIdx.x - NG / 8) * 64;
    int tr = t >> 4, tc = t & 15;
    float acc[4][4] = {};
    for (int k0 = 0; k0 < 128; k0 += 16) {
        {   int r = t >> 2, kq = t & 3;
            float4 v = *(const float4*)&X[(size_t)(row0 + r) * 128 + k0 + kq * 4];
            As[kq * 4 + 0][r] = v.x; As[kq * 4 + 1][r] = v.y;
            As[kq * 4 + 2][r] = v.z; As[kq * 4 + 3][r] = v.w;
        }
        {   int k = t >> 4, cq = t & 15;
            float4 v = *(const float4*)&W[(size_t)(k0 + k) * 64 + cq * 4];
            *(float4*)&Bs[k][cq * 4] = v;
        }
        __syncthreads();
        #pragma unroll
        for (int k = 0; k < 16; k++) {
            float a0 = As[k][tr * 4 + 0], a1 = As[k][tr * 4 + 1];
            float a2 = As[k][tr * 4 + 2], a3 = As[k][tr * 4 + 3];
            float b0 = Bs[k][tc * 4 + 0], b1 = Bs[k][tc * 4 + 1];
            float b2 = Bs[k][tc * 4 + 2], b3 = Bs[k][tc * 4 + 3];
            acc[0][0] += a0 * b0; acc[0][1] += a0 * b1; acc[0][2] += a0 * b2; acc[0][3] += a0 * b3;
            acc[1][0] += a1 * b0; acc[1][1] += a1 * b1; acc[1][2] += a1 * b2; acc[1][3] += a1 * b3;
            acc[2][0] += a2 * b0; acc[2][1] += a2 * b1; acc[2][2] += a2 * b2; acc[2][3] += a2 * b3;
            acc[3][0] += a3 * b0; acc[3][1] += a3 * b1; acc[3][2] += a3 * b2; acc[3][3] += a3 * b3;
        }
        __syncthreads();
    }
    #pragma unroll
    for (int i = 0; i < 4; i++) {
        int rr = row0 + tr * 4 + i;
        int sub = rowlist[rr] >> 10;
        const float4 aw = *(const float4*)&AW[(size_t)sub * 64 + tc * 4];
        float4 v = { acc[i][0] + aw.x, acc[i][1] + aw.y, acc[i][2] + aw.z, acc[i][3] + aw.w };
        *(float4*)&Y[(size_t)rr * 64 + tc * 4] = v;
    }
}

// hf[g] = sum_p X2Ws[p]  -- pure streaming segmented sum
__global__ __launch_bounds__(256) void k_gatherH(const float4* __restrict__ X2Ws,
        const int* __restrict__ rowptrR, float4* __restrict__ hf) {
    int t = threadIdx.x;
    int g = blockIdx.x * 16 + (t >> 4);
    int f4 = t & 15;
    int st = rowptrR[g], en = rowptrR[g + 1];
    float4 acc = {0.f, 0.f, 0.f, 0.f};
    for (int p = st; p < en; p++) {
        float4 a = X2Ws[(size_t)p * 16 + f4];
        acc.x += a.x; acc.y += a.y; acc.z += a.z; acc.w += a.w;
    }
    hf[(size_t)g * 16 + f4] = acc;
}

// final GCN aggregate + bias + log_softmax (64 classes = 16 float4 lanes)
__global__ __launch_bounds__(256) void k_final(const float4* __restrict__ hf,
        const float* __restrict__ dinvN, const int* __restrict__ rowptr,
        const int* __restrict__ col, const float* __restrict__ bfb,
        float4* __restrict__ out) {
    int t = threadIdx.x;
    int n = blockIdx.x * 16 + (t >> 4);
    int f4 = t & 15;
    int st = rowptr[n], en = rowptr[n + 1];
    float4 acc = {0.f, 0.f, 0.f, 0.f};
    for (int p = st; p < en; p++) {
        int src = col[p];
        float d = dinvN[src];
        float4 hv = hf[(size_t)src * 16 + f4];
        acc.x += hv.x * d; acc.y += hv.y * d; acc.z += hv.z * d; acc.w += hv.w * d;
    }
    float dn = dinvN[n];
    float dn2 = dn * dn;
    float4 hs = hf[(size_t)n * 16 + f4];
    float4 bb = ((const float4*)bfb)[f4];
    float4 x;
    x.x = acc.x * dn + hs.x * dn2 + bb.x;
    x.y = acc.y * dn + hs.y * dn2 + bb.y;
    x.z = acc.z * dn + hs.z * dn2 + bb.z;
    x.w = acc.w * dn + hs.w * dn2 + bb.w;
    float m = fmaxf(fmaxf(x.x, x.y), fmaxf(x.z, x.w));
    for (int o = 1; o < 16; o <<= 1) m = fmaxf(m, __shfl_xor(m, o, 64));
    float ssum = expf(x.x - m) + expf(x.y - m) + expf(x.z - m) + expf(x.w - m);
    for (int o = 1; o < 16; o <<= 1) ssum += __shfl_xor(ssum, o, 64);
    float lz = m + logf(ssum);
    float4 r = { x.x - lz, x.y - lz, x.z - lz, x.w - lz };
    out[(size_t)n * 16 + f4] = r;
}

// ---------------- host ----------------
extern "C" void kernel_launch(void* const* d_in, const int* in_sizes, int n_in,
                              void* d_out, int out_size, void* d_ws, size_t ws_size,
                              hipStream_t stream) {
    const float* sub_x = (const float*)d_in[0];
    const int*   sei   = (const int*)d_in[1];
    const int*   sorig = (const int*)d_in[2];
    const int*   gei   = (const int*)d_in[3];
    const float *W1 = (const float*)d_in[4],  *b1  = (const float*)d_in[5];
    const float *W2 = (const float*)d_in[6],  *b2  = (const float*)d_in[7];
    const float *Wp = (const float*)d_in[8],  *bp  = (const float*)d_in[9];
    const float *Wsc = (const float*)d_in[10], *bsc = (const float*)d_in[11];
    const float *Wqkv = (const float*)d_in[12], *bqkv = (const float*)d_in[13];
    const float *Wo = (const float*)d_in[14], *bo  = (const float*)d_in[15];
    const float *Wf = (const float*)d_in[16], *bfb = (const float*)d_in[17];

    float* out0 = (float*)d_out;                      // log-softmax [NG,64]
    float* gemb = (float*)d_out + (size_t)NG * 64;    // global_emb [NG,384] in-place

    char* w = (char*)d_ws;
    size_t off = 0;
    auto alloc = [&](size_t nbytes) -> void* {
        off = (off + 255) & ~(size_t)255;
        void* p = w + off;
        off += nbytes;
        return p;
    };
    // bcur + cntR adjacent -> single memset covers both
    int*   bcur    = (int*)alloc(64 * 4);              // counts (init 0)
    int*   cntR    = (int*)alloc((size_t)NG * 4);
    float* AW      = (float*)alloc((size_t)S * 64 * 4);
    float* dinv    = (float*)alloc((size_t)NG * 4);        // subgraph dinv; later dinvN
    float* scoreh  = (float*)alloc((size_t)NG * 4);
    float* score   = (float*)alloc((size_t)NG * 4);
    float* gate    = (float*)alloc((size_t)S * KSEL * 4);
    float* dinv2   = (float*)alloc((size_t)S * KSEL * 4);
    float* subemb  = (float*)alloc((size_t)S * 256 * 4);
    float* att     = (float*)alloc((size_t)S * 256 * 4);
    int*   perm    = (int*)alloc((size_t)S * KSEL * 4);
    int*   posmap  = (int*)alloc((size_t)NG * 4);
    int*   cur_sub = (int*)alloc((size_t)NG * 4);          // used as curR
    int*   rowptr_s= (int*)alloc((size_t)(NG + 64) * 4);   // alias: rowptrN
    int*   col_sub = (int*)alloc((size_t)EG * 4);          // alias: colN
    int*   rowptrR = (int*)alloc((size_t)(NG + 64) * 4);
    int*   rowlist = (int*)alloc((size_t)NG * 4);
    int*   posR    = (int*)alloc((size_t)NG * 4);
    float* x1      = (float*)alloc((size_t)NG * NH * 4);   // alias: xsub, later X2Ws
    float* x2s     = (float*)alloc((size_t)NG * NH * 4);   // GCN2 out, PERMUTED to rowlist order
    float* hbuf    = (float*)alloc((size_t)NG * NH * 4);   // alias: hf
    float* xpool   = (float*)alloc((size_t)S * KSEL * NH * 4);  // alias: ebin
    float* xsub    = x1;
    float* hf      = hbuf;
    float* dinvN   = dinv;
    float* X2Ws    = x1;                                   // x1 dead after k_ea_fb
    int*   curR    = cur_sub;
    int*   rowptrN = rowptr_s;
    int*   colN    = col_sub;
    int*   ebin    = (int*)xpool;                          // xpool dead after k_emb_mmP

    hipMemsetAsync(bcur, 0, 256 + (size_t)NG * 4, stream);   // bcur + cntR in one

    // csr_sub + countR || mm1 first half; scanR || mm1 second half; fillR
    k_csr_mm1<<<384, 1024, 0, stream>>>(sei, sorig, rowptr_s, col_sub, dinv, cntR,
                                        sub_x, W1, hbuf);
    k_scan_mm1<<<320, 1024, 0, stream>>>(cntR, rowptrR, curR, sub_x, W1, hbuf);
    k_fillR<<<NG / 256, 256, 0, stream>>>(sorig, curR, rowlist, posR);

    // GCN1 aggregate (+ fused scorer h = x1 @ Wp)
    k_agg1<<<8192, 256, 0, stream>>>((const float4*)hbuf, dinv, rowptr_s, col_sub,
                                     b1, Wp, (float4*)x1, scoreh);
    // GCN2 matmul || score_agg
    k_mm2s<<<2048 + NG / 256, 256, 0, stream>>>(x1, W2, hbuf,
                                                scoreh, dinv, rowptr_s, col_sub, bp, score);
    // GCN2 aggregate (rowlist-order scatter) || top-K
    k_agg2_topk<<<4096 + S, 512, 0, stream>>>((const float4*)hbuf, dinv, rowptr_s, col_sub,
                                              b2, posR, (float4*)x2s,
                                              score, perm, gate, posmap);
    // pooling
    k_pool<<<(S * KSEL) / 8, 256, 0, stream>>>((const float4*)x1, perm, gate, posmap,
                                               rowptr_s, col_sub, dinv2, (float4*)xpool);
    // emb pass 1 || mmP (xpool @ Wsc)
    k_emb_mmP<<<64 + (S * KSEL) / 128, 1024, 0, stream>>>(xpool, subemb, Wsc, hbuf);
    // pooled aggregate || binN
    k_aggp_bin<<<4096 + EG / 8192, 256, 0, stream>>>((const float4*)hbuf, dinv2, perm, posmap,
                                                     rowptr_s, col_sub, bsc, (float4*)xsub,
                                                     gei, bcur, ebin);
    // emb pass2 + attention + AW || fillB3
    k_ea_fb<<<128, 1024, 0, stream>>>(xsub, subemb, Wqkv, bqkv, Wo, bo, Wf, att, AW,
                                      ebin, bcur, rowptrN, dinvN, colN);
    // streaming gather of gemb || X2Ws matmul (+AW fold)
    k_gx<<<NG / 8 + NG / 64, 256, 0, stream>>>((const float4*)x2s, (const float4*)att,
                                               rowptrR, rowlist, (float4*)gemb,
                                               x2s, Wf, AW, X2Ws);
    k_gatherH<<<NG / 16, 256, 0, stream>>>((const float4*)X2Ws, rowptrR, (float4*)hf);

    // final GCN + log_softmax
    k_final<<<NG / 16, 256, 0, stream>>>((const float4*)hf, dinvN, rowptrN, colN, bfb, (float4*)out0);

    (void)in_sizes; (void)n_in; (void)out_size; (void)ws_size;
}

// Round 9
// 585.758 us; speedup vs baseline: 1.2657x; 1.1329x over previous
//
#include <hip/hip_runtime.h>
#include <math.h>

#define S     64
#define NSUB  1024
#define ESUB  16384
#define NG    65536
#define EG    1048576
#define NH    128
#define KSEL  512
#define BCAP  20480   // per-bucket ebin capacity; bucket ~ Binom(1M,1/64): mean 16384, sd 127

// ---- 1024-thread 128x128-tile matmul (KDIM=NCOL=128). k ascends exactly like the
// 64x64 256-thr version -> bitwise-identical per-element accumulation order.
__device__ __forceinline__ void mm1024_tile(const float* __restrict__ X,
        const float* __restrict__ W, float* __restrict__ Y, int row0, int t,
        float (*As)[136], float (*Bs)[136]) {
    int tr = t >> 5, tc = t & 31;
    float acc[4][4] = {};
    for (int k0 = 0; k0 < 128; k0 += 16) {
        if (t < 512) {                               // stage A: 128 rows x 16 k
            int r = t >> 2, kq = t & 3;
            float4 v = *(const float4*)&X[(size_t)(row0 + r) * 128 + k0 + kq * 4];
            As[kq * 4 + 0][r] = v.x; As[kq * 4 + 1][r] = v.y;
            As[kq * 4 + 2][r] = v.z; As[kq * 4 + 3][r] = v.w;
        } else {                                     // stage B: 16 k x 128 cols
            int u = t - 512;
            int k = u >> 5, c = (u & 31) * 4;
            *(float4*)&Bs[k][c] = *(const float4*)&W[(size_t)(k0 + k) * 128 + c];
        }
        __syncthreads();
        #pragma unroll
        for (int k = 0; k < 16; k++) {
            float a0 = As[k][tr * 4 + 0], a1 = As[k][tr * 4 + 1];
            float a2 = As[k][tr * 4 + 2], a3 = As[k][tr * 4 + 3];
            float b0 = Bs[k][tc * 4 + 0], b1 = Bs[k][tc * 4 + 1];
            float b2 = Bs[k][tc * 4 + 2], b3 = Bs[k][tc * 4 + 3];
            acc[0][0] += a0 * b0; acc[0][1] += a0 * b1; acc[0][2] += a0 * b2; acc[0][3] += a0 * b3;
            acc[1][0] += a1 * b0; acc[1][1] += a1 * b1; acc[1][2] += a1 * b2; acc[1][3] += a1 * b3;
            acc[2][0] += a2 * b0; acc[2][1] += a2 * b1; acc[2][2] += a2 * b2; acc[2][3] += a2 * b3;
            acc[3][0] += a3 * b0; acc[3][1] += a3 * b1; acc[3][2] += a3 * b2; acc[3][3] += a3 * b3;
        }
        __syncthreads();
    }
    #pragma unroll
    for (int i = 0; i < 4; i++) {
        float4 v = { acc[i][0], acc[i][1], acc[i][2], acc[i][3] };
        *(float4*)&Y[(size_t)(row0 + tr * 4 + i) * 128 + tc * 4] = v;
    }
}

// ---- fused: blocks [0,64) per-subgraph CSR; [64,128) countR; [128,384) mm1 tiles 0-255
__global__ __launch_bounds__(1024) void k_csr_mm1(const int* __restrict__ sei,
        const int* __restrict__ sorig, int* __restrict__ rowptr, int* __restrict__ col,
        float* __restrict__ dinv, int* __restrict__ cntR,
        const float* __restrict__ X, const float* __restrict__ W, float* __restrict__ Y) {
    __shared__ float As[16][136];
    __shared__ float Bs[16][136];
    __shared__ int sh[1024];
    __shared__ int curL[1024];
    int b = blockIdx.x, t = threadIdx.x;
    if (b >= 128) {                                  // mm1 first half (rows 0..32767)
        mm1024_tile(X, W, Y, (b - 128) * 128, t, As, Bs);
        return;
    }
    if (b >= 64) {                                   // folded countR (NG entries)
        int r = (b - 64) * 1024 + t;
        atomicAdd(&cntR[sorig[r]], 1);
        return;
    }
    int s = b;
    curL[t] = 0;
    __syncthreads();
    const int* dstp = sei + s * 2 * ESUB + ESUB;
    #pragma unroll
    for (int k = 0; k < 16; k++) atomicAdd(&curL[dstp[k * 1024 + t]], 1);
    __syncthreads();
    int v = curL[t];
    sh[t] = v;
    __syncthreads();
    for (int off = 1; off < 1024; off <<= 1) {
        int add = (t >= off) ? sh[t - off] : 0;
        __syncthreads();
        sh[t] += add;
        __syncthreads();
    }
    int incl = sh[t];
    int excl = incl - v;
    rowptr[s * (NSUB + 1) + t] = excl;
    dinv[s * NSUB + t] = rsqrtf((float)(v + 1));     // deg = indeg + 1 (self loop)
    if (t == 1023) rowptr[s * (NSUB + 1) + NSUB] = incl;
    curL[t] = s * ESUB + excl;                       // absolute cursor
    __syncthreads();
    const int* srcp = sei + s * 2 * ESUB;
    #pragma unroll
    for (int k = 0; k < 16; k++) {
        int e = k * 1024 + t;
        int src = srcp[e];
        int dst = dstp[e];
        int p = atomicAdd(&curL[dst], 1);
        col[p] = src;
    }
}

// ---- fused: blocks [0,64) scanR (p1+p3); [64,320) mm1 tiles 256-511 ----------
__global__ __launch_bounds__(1024) void k_scan_mm1(const int* __restrict__ cnt,
        int* __restrict__ rowptr, int* __restrict__ cur,
        const float* __restrict__ X, const float* __restrict__ W, float* __restrict__ Y) {
    __shared__ float As[16][136];
    __shared__ float Bs[16][136];
    __shared__ int sh[1024];
    __shared__ int wsum[16];
    __shared__ int sboff;
    int b = blockIdx.x, t = threadIdx.x;
    if (b >= 64) {                                   // mm1 second half (rows 32768..65535)
        mm1024_tile(X, W, Y, (b - 64 + 256) * 128, t, As, Bs);
        return;
    }
    int pre = 0;
    for (int i = t; i < b * 1024; i += 1024) pre += cnt[i];
    #pragma unroll
    for (int o = 32; o > 0; o >>= 1) pre += __shfl_xor(pre, o, 64);
    if ((t & 63) == 0) wsum[t >> 6] = pre;
    __syncthreads();
    if (t == 0) {
        int r = 0;
        #pragma unroll
        for (int i = 0; i < 16; i++) r += wsum[i];
        sboff = r;
    }
    int v = cnt[b * 1024 + t];
    sh[t] = v;
    __syncthreads();
    for (int off = 1; off < 1024; off <<= 1) {
        int add = (t >= off) ? sh[t - off] : 0;
        __syncthreads();
        sh[t] += add;
        __syncthreads();
    }
    int base = sboff;
    int r = base + sh[t] - v;
    int idx = b * 1024 + t;
    rowptr[idx] = r;
    cur[idx] = r;
    if (b == 63 && t == 1023) rowptr[NG] = base + sh[t];   // = NG
}

// fillR: rowlist (pos->row) AND posR (row->pos) for producer-side permutation
__global__ void k_fillR(const int* __restrict__ orig, int* __restrict__ cur,
                        int* __restrict__ rowlist, int* __restrict__ posR) {
    int r = blockIdx.x * 256 + threadIdx.x;          // < NG
    int p = atomicAdd(&cur[orig[r]], 1);
    rowlist[p] = r;
    posR[r] = p;
}

// unrolled-by-4 GCN edge aggregate (order-preserving; 4 h-loads in flight)
__device__ __forceinline__ float4 agg_edges4(const float4* __restrict__ h, size_t hb,
        const int* __restrict__ cl, const float* __restrict__ dv,
        int st, int en, int f4) {
    float4 acc = {0.f, 0.f, 0.f, 0.f};
    int p = st;
    for (; p + 4 <= en; p += 4) {
        int s0 = cl[p + 0], s1 = cl[p + 1], s2 = cl[p + 2], s3 = cl[p + 3];
        float d0 = dv[s0], d1 = dv[s1], d2 = dv[s2], d3 = dv[s3];
        float4 h0 = h[(hb + s0) * 32 + f4];
        float4 h1 = h[(hb + s1) * 32 + f4];
        float4 h2 = h[(hb + s2) * 32 + f4];
        float4 h3 = h[(hb + s3) * 32 + f4];
        acc.x += h0.x * d0; acc.y += h0.y * d0; acc.z += h0.z * d0; acc.w += h0.w * d0;
        acc.x += h1.x * d1; acc.y += h1.y * d1; acc.z += h1.z * d1; acc.w += h1.w * d1;
        acc.x += h2.x * d2; acc.y += h2.y * d2; acc.z += h2.z * d2; acc.w += h2.w * d2;
        acc.x += h3.x * d3; acc.y += h3.y * d3; acc.z += h3.z * d3; acc.w += h3.w * d3;
    }
    for (; p < en; p++) {
        int src = cl[p];
        float d = dv[src];
        float4 hv = h[(hb + src) * 32 + f4];
        acc.x += hv.x * d; acc.y += hv.y * d; acc.z += hv.z * d; acc.w += hv.w * d;
    }
    return acc;
}

// ---- fused: blocks [0,256) score_agg (short, first); [256,2304) matmul2 64x64 tiles ----
__global__ __launch_bounds__(256) void k_mm2s(const float* __restrict__ X,
        const float* __restrict__ W, float* __restrict__ Y,
        const float* __restrict__ sh, const float* __restrict__ dinv,
        const int* __restrict__ rowptr, const int* __restrict__ col,
        const float* __restrict__ bp, float* __restrict__ score) {
    int t = threadIdx.x;
    if (blockIdx.x < 256) {                          // score_agg (unrolled x4)
        int n = blockIdx.x * 256 + t;
        int s = n >> 10, nl = n & (NSUB - 1);
        const int* rp = rowptr + s * (NSUB + 1);
        const int* cl = col + s * ESUB;
        const float* dv = dinv + s * NSUB;
        const float* shs = sh + s * NSUB;
        int st = rp[nl], en = rp[nl + 1];
        float acc = 0.f;
        int p = st;
        for (; p + 4 <= en; p += 4) {
            int s0 = cl[p + 0], s1 = cl[p + 1], s2 = cl[p + 2], s3 = cl[p + 3];
            float v0 = shs[s0] * dv[s0];
            float v1 = shs[s1] * dv[s1];
            float v2 = shs[s2] * dv[s2];
            float v3 = shs[s3] * dv[s3];
            acc += v0; acc += v1; acc += v2; acc += v3;
        }
        for (; p < en; p++) {
            int src = cl[p];
            acc += shs[src] * dv[src];
        }
        float dn = dv[nl];
        score[n] = acc * dn + sh[n] * dn * dn + bp[0];
        return;
    }
    __shared__ float As[16][72];
    __shared__ float Bs[16][72];
    int bb = blockIdx.x - 256;
    int row0 = (bb & 1023) * 64;
    int col0 = (bb >> 10) * 64;
    int tr = t >> 4, tc = t & 15;
    float acc[4][4] = {};
    for (int k0 = 0; k0 < 128; k0 += 16) {
        {   int r = t >> 2, kq = t & 3;
            float4 v = *(const float4*)&X[(size_t)(row0 + r) * 128 + k0 + kq * 4];
            As[kq * 4 + 0][r] = v.x; As[kq * 4 + 1][r] = v.y;
            As[kq * 4 + 2][r] = v.z; As[kq * 4 + 3][r] = v.w;
        }
        {   int k = t >> 4, cq = t & 15;
            float4 v = *(const float4*)&W[(size_t)(k0 + k) * 128 + col0 + cq * 4];
            *(float4*)&Bs[k][cq * 4] = v;
        }
        __syncthreads();
        #pragma unroll
        for (int k = 0; k < 16; k++) {
            float a0 = As[k][tr * 4 + 0], a1 = As[k][tr * 4 + 1];
            float a2 = As[k][tr * 4 + 2], a3 = As[k][tr * 4 + 3];
            float b0 = Bs[k][tc * 4 + 0], b1 = Bs[k][tc * 4 + 1];
            float b2 = Bs[k][tc * 4 + 2], b3 = Bs[k][tc * 4 + 3];
            acc[0][0] += a0 * b0; acc[0][1] += a0 * b1; acc[0][2] += a0 * b2; acc[0][3] += a0 * b3;
            acc[1][0] += a1 * b0; acc[1][1] += a1 * b1; acc[1][2] += a1 * b2; acc[1][3] += a1 * b3;
            acc[2][0] += a2 * b0; acc[2][1] += a2 * b1; acc[2][2] += a2 * b2; acc[2][3] += a2 * b3;
            acc[3][0] += a3 * b0; acc[3][1] += a3 * b1; acc[3][2] += a3 * b2; acc[3][3] += a3 * b3;
        }
        __syncthreads();
    }
    #pragma unroll
    for (int i = 0; i < 4; i++) {
        float4 v = { acc[i][0], acc[i][1], acc[i][2], acc[i][3] };
        *(float4*)&Y[(size_t)(row0 + tr * 4 + i) * 128 + col0 + tc * 4] = v;
    }
}

// ------- GCN aggregate 1 (+ fused scorer); 256-thr, 8 nodes/block, unrolled x4 ----
__global__ __launch_bounds__(256) void k_agg1(const float4* __restrict__ h,
        const float* __restrict__ dinv, const int* __restrict__ rowptr,
        const int* __restrict__ col, const float* __restrict__ bias,
        const float* __restrict__ Wp, float4* __restrict__ out,
        float* __restrict__ scoreh) {
    int b = blockIdx.x;
    int s = b & 63;                      // subgraph -> fixed XCD (b%8 == s%8)
    int chunk = b >> 6;
    int t = threadIdx.x;
    int nl = chunk * 8 + (t >> 5);
    int f4 = t & 31;
    const int* rp = rowptr + s * (NSUB + 1);
    int st = rp[nl], en = rp[nl + 1];
    float4 acc = agg_edges4(h, (size_t)s * NSUB, col + s * ESUB, dinv + s * NSUB, st, en, f4);
    size_t node = (size_t)s * NSUB + nl;
    const float* dv = dinv + s * NSUB;
    float dn = dv[nl];
    float dn2 = dn * dn;
    float4 hs = h[node * 32 + f4];
    float4 bb = ((const float4*)bias)[f4];
    float4 r;
    r.x = fmaxf(acc.x * dn + hs.x * dn2 + bb.x, 0.f);
    r.y = fmaxf(acc.y * dn + hs.y * dn2 + bb.y, 0.f);
    r.z = fmaxf(acc.z * dn + hs.z * dn2 + bb.z, 0.f);
    r.w = fmaxf(acc.w * dn + hs.w * dn2 + bb.w, 0.f);
    out[node * 32 + f4] = r;
    float4 wp = ((const float4*)Wp)[f4];
    float p = r.x * wp.x + r.y * wp.y + r.z * wp.z + r.w * wp.w;
    #pragma unroll
    for (int o = 16; o > 0; o >>= 1) p += __shfl_xor(p, o, 32);
    if (f4 == 0) scoreh[node] = p;
}

// ---- fused: blocks [0,64) top-K (short, FIRST); [64,4160) agg2 (512-thr, 16 nodes) ----
__global__ __launch_bounds__(512) void k_topk_agg2(const float4* __restrict__ h,
        const float* __restrict__ dinv, const int* __restrict__ rowptr,
        const int* __restrict__ col, const float* __restrict__ bias,
        const int* __restrict__ posR, float4* __restrict__ out,
        const float* __restrict__ score, int* __restrict__ perm,
        float* __restrict__ gate, int* __restrict__ posmap) {
    int t = threadIdx.x;
    if (blockIdx.x < 64) {                           // topk
        __shared__ float sv[1024];
        __shared__ int   si[1024];
        int s = blockIdx.x;
        for (int i = t; i < 1024; i += 512) {
            sv[i] = score[s * NSUB + i];
            si[i] = i;
            posmap[s * NSUB + i] = -1;
        }
        __syncthreads();
        for (int k = 2; k <= 1024; k <<= 1) {
            for (int j = k >> 1; j > 0; j >>= 1) {
                for (int b = t; b < 1024; b += 512) {
                    int ixj = b ^ j;
                    if (ixj > b) {
                        bool desc = ((b & k) == 0);
                        bool sw = desc ? (sv[b] < sv[ixj]) : (sv[b] > sv[ixj]);
                        if (sw) {
                            float tv = sv[b]; sv[b] = sv[ixj]; sv[ixj] = tv;
                            int ti = si[b]; si[b] = si[ixj]; si[ixj] = ti;
                        }
                    }
                }
                __syncthreads();
            }
        }
        if (t < KSEL) {
            perm[s * KSEL + t] = si[t];
            gate[s * KSEL + t] = tanhf(sv[t]);
            posmap[s * NSUB + si[t]] = t;
        }
        return;
    }
    int b = blockIdx.x - 64;
    int s = b & 63;
    int chunk = b >> 6;                              // 0..63
    int nl = chunk * 16 + (t >> 5);
    int f4 = t & 31;
    const int* rp = rowptr + s * (NSUB + 1);
    int st = rp[nl], en = rp[nl + 1];
    float4 acc = agg_edges4(h, (size_t)s * NSUB, col + s * ESUB, dinv + s * NSUB, st, en, f4);
    size_t node = (size_t)s * NSUB + nl;
    const float* dv = dinv + s * NSUB;
    float dn = dv[nl];
    float dn2 = dn * dn;
    float4 hs = h[node * 32 + f4];
    float4 bb = ((const float4*)bias)[f4];
    float4 r;
    r.x = fmaxf(acc.x * dn + hs.x * dn2 + bb.x, 0.f);
    r.y = fmaxf(acc.y * dn + hs.y * dn2 + bb.y, 0.f);
    r.z = fmaxf(acc.z * dn + hs.z * dn2 + bb.z, 0.f);
    r.w = fmaxf(acc.w * dn + hs.w * dn2 + bb.w, 0.f);
    out[(size_t)posR[node] * 32 + f4] = r;           // rowlist-order scatter write
}

// fused deg2 + xpool
__global__ __launch_bounds__(256) void k_pool(const float4* __restrict__ x1,
        const int* __restrict__ perm, const float* __restrict__ gate,
        const int* __restrict__ posmap, const int* __restrict__ rowptr,
        const int* __restrict__ col, float* __restrict__ dinv2,
        float4* __restrict__ xpool) {
    int t = threadIdx.x;
    int i = blockIdx.x * 8 + (t >> 5);
    int lane = t & 31;
    int s = i >> 9;
    int n = perm[i];
    const int* rp = rowptr + s * (NSUB + 1);
    const int* cl = col + s * ESUB;
    int st = rp[n], en = rp[n + 1];
    int c = 0;
    for (int p = st + lane; p < en; p += 32) c += (posmap[s * NSUB + cl[p]] >= 0) ? 1 : 0;
    #pragma unroll
    for (int o = 16; o > 0; o >>= 1) c += __shfl_xor(c, o, 32);
    if (lane == 0) dinv2[i] = rsqrtf((float)(c + 1));
    float g = gate[i];
    float4 v = x1[((size_t)(s * NSUB + n)) * 32 + lane];
    v.x *= g; v.y *= g; v.z *= g; v.w *= g;
    xpool[(size_t)i * 32 + lane] = v;
}

// ---- fused: blocks [0,64) emb pass 1; [64,320) mmP (xpool @ Wsc, 128-tiles) ----
__global__ __launch_bounds__(1024) void k_emb_mmP(const float* __restrict__ X,
        float* __restrict__ out, const float* __restrict__ W, float* __restrict__ Y) {
    __shared__ float As[16][136];
    __shared__ float Bs[16][136];
    __shared__ float red[4][256];
    int b = blockIdx.x, t = threadIdx.x;
    if (b >= 64) {                                   // mmP: S*KSEL rows
        mm1024_tile(X, W, Y, (b - 64) * 128, t, As, Bs);
        return;
    }
    int s = b;
    int sl = t >> 8, f = t & 255;
    const float* base = X + (size_t)s * KSEL * NH;
    float r;
    if (f < NH) {
        r = -INFINITY;
        for (int i = sl * 128; i < sl * 128 + 128; i++) r = fmaxf(r, base[i * NH + f]);
    } else {
        r = 0.f;
        for (int i = sl * 128; i < sl * 128 + 128; i++) r += base[i * NH + (f - NH)];
    }
    red[sl][f] = r;
    __syncthreads();
    if (sl == 0) {
        float a = red[0][f], bb = red[1][f], c = red[2][f], d = red[3][f];
        float v = (f < NH) ? fmaxf(fmaxf(a, bb), fmaxf(c, d)) : (a + bb + c + d) * (1.f / KSEL);
        out[s * 256 + f] = v;
    }
}

// ---- fused: blocks [0,128) binN (short, FIRST); [128,4224) pooled GCN aggregate ----
__global__ __launch_bounds__(256) void k_aggp_bin(const float4* __restrict__ hp,
        const float* __restrict__ dinv2, const int* __restrict__ perm,
        const int* __restrict__ posmap, const int* __restrict__ rowptr,
        const int* __restrict__ col, const float* __restrict__ bsc,
        float4* __restrict__ xsub,
        const int* __restrict__ gei, int* __restrict__ bcur, int* __restrict__ ebin) {
    int t = threadIdx.x;
    if (blockIdx.x < 128) {                          // binN (count-based bcur, memset-0)
        __shared__ int lh[64];
        __shared__ int lbase[64];
        if (t < 64) lh[t] = 0;
        __syncthreads();
        int e0 = blockIdx.x * 8192;
        #pragma unroll 8
        for (int k = 0; k < 32; k++) {
            int d = gei[EG + e0 + k * 256 + t];
            atomicAdd(&lh[d >> 10], 1);
        }
        __syncthreads();
        if (t < 64) {
            lbase[t] = t * BCAP + atomicAdd(&bcur[t], lh[t]);
            lh[t] = 0;
        }
        __syncthreads();
        #pragma unroll 4
        for (int k = 0; k < 32; k++) {
            int idx = e0 + k * 256 + t;
            int d = gei[EG + idx];
            int src = gei[idx];
            int bb = d >> 10;
            int pos = lbase[bb] + atomicAdd(&lh[bb], 1);
            ebin[pos] = src | ((d & 1023) << 16);
        }
        return;
    }
    int b = blockIdx.x - 128;
    int s = b & 63;
    int chunk = b >> 6;
    int il = chunk * 8 + (t >> 5);
    int f4 = t & 31;
    int i = s * KSEL + il;
    int n = perm[i];
    const int* rp = rowptr + s * (NSUB + 1);
    const int* cl = col + s * ESUB;
    const int* pm = posmap + s * NSUB;
    const float* dv2 = dinv2 + s * KSEL;
    size_t hb = (size_t)s * KSEL;
    int st = rp[n], en = rp[n + 1];
    float4 acc = {0.f, 0.f, 0.f, 0.f};
    int p = st;
    for (; p + 4 <= en; p += 4) {
        int j0 = pm[cl[p + 0]], j1 = pm[cl[p + 1]], j2 = pm[cl[p + 2]], j3 = pm[cl[p + 3]];
        int i0 = j0 >= 0 ? j0 : 0, i1 = j1 >= 0 ? j1 : 0;
        int i2 = j2 >= 0 ? j2 : 0, i3 = j3 >= 0 ? j3 : 0;
        float d0 = j0 >= 0 ? dv2[i0] : 0.f;          // +0 contribution == ref's ew=0 edge
        float d1 = j1 >= 0 ? dv2[i1] : 0.f;
        float d2 = j2 >= 0 ? dv2[i2] : 0.f;
        float d3 = j3 >= 0 ? dv2[i3] : 0.f;
        float4 h0 = hp[(hb + i0) * 32 + f4];
        float4 h1 = hp[(hb + i1) * 32 + f4];
        float4 h2 = hp[(hb + i2) * 32 + f4];
        float4 h3 = hp[(hb + i3) * 32 + f4];
        acc.x += h0.x * d0; acc.y += h0.y * d0; acc.z += h0.z * d0; acc.w += h0.w * d0;
        acc.x += h1.x * d1; acc.y += h1.y * d1; acc.z += h1.z * d1; acc.w += h1.w * d1;
        acc.x += h2.x * d2; acc.y += h2.y * d2; acc.z += h2.z * d2; acc.w += h2.w * d2;
        acc.x += h3.x * d3; acc.y += h3.y * d3; acc.z += h3.z * d3; acc.w += h3.w * d3;
    }
    for (; p < en; p++) {
        int j = pm[cl[p]];
        if (j >= 0) {
            float d = dv2[j];
            float4 hv = hp[(hb + j) * 32 + f4];
            acc.x += hv.x * d; acc.y += hv.y * d; acc.z += hv.z * d; acc.w += hv.w * d;
        }
    }
    float dn = dinv2[i];
    float dn2 = dn * dn;
    float4 hs = hp[(size_t)i * 32 + f4];
    float4 bb = ((const float4*)bsc)[f4];
    float4 r;
    r.x = fmaxf(acc.x * dn + hs.x * dn2 + bb.x, 0.f);
    r.y = fmaxf(acc.y * dn + hs.y * dn2 + bb.y, 0.f);
    r.z = fmaxf(acc.z * dn + hs.z * dn2 + bb.z, 0.f);
    r.w = fmaxf(acc.w * dn + hs.w * dn2 + bb.w, 0.f);
    xsub[(size_t)i * 32 + f4] = r;
}

// ---- fused: blocks [0,64) emb_attn (pass2 + attention + AW); [64,128) fillB3 ----
// (128 blocks total at 1024 thr -> all resident from t=0; order irrelevant)
__global__ __launch_bounds__(1024) void k_ea_fb(const float* __restrict__ X,
        const float* __restrict__ subemb, const float* __restrict__ Wqkv,
        const float* __restrict__ bqkv, const float* __restrict__ Wo,
        const float* __restrict__ bo, const float* __restrict__ Wf,
        float* __restrict__ att, float* __restrict__ AW,
        const int* __restrict__ ebin, const int* __restrict__ bcur,
        int* __restrict__ rowptrN, float* __restrict__ dinvN, int* __restrict__ colN) {
    int t = threadIdx.x;
    if (blockIdx.x >= 64) {
        __shared__ int sh2[1024];
        __shared__ int curL[1024];
        __shared__ int sbase;
        int b = blockIdx.x - 64;
        if (t == 0) {
            int run = 0;
            for (int i = 0; i < b; i++) run += bcur[i];
            sbase = run;
        }
        curL[t] = 0;
        __syncthreads();
        int st = b * BCAP, en = st + bcur[b];
        for (int i = st + t; i < en; i += 1024) atomicAdd(&curL[ebin[i] >> 16], 1);
        __syncthreads();
        int v = curL[t];
        sh2[t] = v;
        __syncthreads();
        for (int off = 1; off < 1024; off <<= 1) {
            int add = (t >= off) ? sh2[t - off] : 0;
            __syncthreads();
            sh2[t] += add;
            __syncthreads();
        }
        int incl = sh2[t];
        int excl = incl - v;
        int base = sbase;
        rowptrN[(b << 10) + t] = base + excl;
        dinvN[(b << 10) + t] = rsqrtf((float)(v + 1));
        if (b == 63 && t == 1023) rowptrN[NG] = base + incl;   // = EG
        curL[t] = base + excl;
        __syncthreads();
        for (int i = st + t; i < en; i += 1024) {
            int packed = ebin[i];
            int p = atomicAdd(&curL[packed >> 16], 1);
            colN[p] = packed & 0xFFFF;
        }
        return;
    }
    __shared__ float red[4][256];
    __shared__ float se[256], t1[256], av[256];
    int s = blockIdx.x;
    int sl = t >> 8, f = t & 255;
    const float* base = X + (size_t)s * KSEL * NH;
    float r;
    if (f < NH) {
        r = -INFINITY;
        for (int i = sl * 128; i < sl * 128 + 128; i++) r = fmaxf(r, base[i * NH + f]);
    } else {
        r = 0.f;
        for (int i = sl * 128; i < sl * 128 + 128; i++) r += base[i * NH + (f - NH)];
    }
    red[sl][f] = r;
    __syncthreads();
    if (sl == 0) {
        float a = red[0][f], b = red[1][f], c = red[2][f], d = red[3][f];
        float v = (f < NH) ? fmaxf(fmaxf(a, b), fmaxf(c, d)) : (a + b + c + d) * (1.f / KSEL);
        se[f] = subemb[s * 256 + f] + v;
    }
    __syncthreads();
    if (sl == 0) {
        float acc = bqkv[512 + f];
        for (int k = 0; k < 256; k++) acc += se[k] * Wqkv[(size_t)k * 768 + 512 + f];
        t1[f] = acc;
    }
    __syncthreads();
    if (sl == 0) {
        float a2 = bo[f];
        for (int k = 0; k < 256; k++) a2 += t1[k] * Wo[(size_t)k * 256 + f];
        att[s * 256 + f] = a2;
        av[f] = a2;
    }
    __syncthreads();
    if (sl == 0 && f < 64) {
        float acc = 0.f;
        for (int k = 0; k < 256; k++) acc += av[k] * Wf[(size_t)(NH + k) * 64 + f];
        AW[s * 64 + f] = acc;
    }
}

// ---- fused: blocks [0,NG/64) X2Ws matmul (short, FIRST); [NG/64,..) streaming gather ----
__global__ __launch_bounds__(256) void k_gx(const float4* __restrict__ x2s,
        const float4* __restrict__ att, const int* __restrict__ rowptrR,
        const int* __restrict__ rowlist, float4* __restrict__ gemb,
        const float* __restrict__ X, const float* __restrict__ W,
        const float* __restrict__ AW, float* __restrict__ Y) {
    int t = threadIdx.x;
    if (blockIdx.x >= NG / 64) {                     // gather: 8 nodes/blk, 32 lanes each
        int g = (blockIdx.x - NG / 64) * 8 + (t >> 5);
        int lane = t & 31;
        int st = rowptrR[g], en = rowptrR[g + 1];
        float4 a0 = {0.f,0.f,0.f,0.f}, a1 = {0.f,0.f,0.f,0.f}, a2 = {0.f,0.f,0.f,0.f};
        for (int p = st; p < en; p++) {
            float4 v = x2s[(size_t)p * 32 + lane];
            a0.x += v.x; a0.y += v.y; a0.z += v.z; a0.w += v.w;
            int sub = rowlist[p] >> 10;
            float4 w1 = att[(size_t)sub * 64 + lane];
            float4 w2 = att[(size_t)sub * 64 + 32 + lane];
            a1.x += w1.x; a1.y += w1.y; a1.z += w1.z; a1.w += w1.w;
            a2.x += w2.x; a2.y += w2.y; a2.z += w2.z; a2.w += w2.w;
        }
        gemb[(size_t)g * 96 + lane]      = a0;
        gemb[(size_t)g * 96 + 32 + lane] = a1;
        gemb[(size_t)g * 96 + 64 + lane] = a2;
        return;
    }
    __shared__ float As[16][72];
    __shared__ float Bs[16][72];
    int row0 = blockIdx.x * 64;
    int tr = t >> 4, tc = t & 15;
    float acc[4][4] = {};
    for (int k0 = 0; k0 < 128; k0 += 16) {
        {   int r = t >> 2, kq = t & 3;
            float4 v = *(const float4*)&X[(size_t)(row0 + r) * 128 + k0 + kq * 4];
            As[kq * 4 + 0][r] = v.x; As[kq * 4 + 1][r] = v.y;
            As[kq * 4 + 2][r] = v.z; As[kq * 4 + 3][r] = v.w;
        }
        {   int k = t >> 4, cq = t & 15;
            float4 v = *(const float4*)&W[(size_t)(k0 + k) * 64 + cq * 4];
            *(float4*)&Bs[k][cq * 4] = v;
        }
        __syncthreads();
        #pragma unroll
        for (int k = 0; k < 16; k++) {
            float a0 = As[k][tr * 4 + 0], a1 = As[k][tr * 4 + 1];
            float a2 = As[k][tr * 4 + 2], a3 = As[k][tr * 4 + 3];
            float b0 = Bs[k][tc * 4 + 0], b1 = Bs[k][tc * 4 + 1];
            float b2 = Bs[k][tc * 4 + 2], b3 = Bs[k][tc * 4 + 3];
            acc[0][0] += a0 * b0; acc[0][1] += a0 * b1; acc[0][2] += a0 * b2; acc[0][3] += a0 * b3;
            acc[1][0] += a1 * b0; acc[1][1] += a1 * b1; acc[1][2] += a1 * b2; acc[1][3] += a1 * b3;
            acc[2][0] += a2 * b0; acc[2][1] += a2 * b1; acc[2][2] += a2 * b2; acc[2][3] += a2 * b3;
            acc[3][0] += a3 * b0; acc[3][1] += a3 * b1; acc[3][2] += a3 * b2; acc[3][3] += a3 * b3;
        }
        __syncthreads();
    }
    #pragma unroll
    for (int i = 0; i < 4; i++) {
        int rr = row0 + tr * 4 + i;
        int sub = rowlist[rr] >> 10;
        const float4 aw = *(const float4*)&AW[(size_t)sub * 64 + tc * 4];
        float4 v = { acc[i][0] + aw.x, acc[i][1] + aw.y, acc[i][2] + aw.z, acc[i][3] + aw.w };
        *(float4*)&Y[(size_t)rr * 64 + tc * 4] = v;
    }
}

// hf[g] = sum_p X2Ws[p]  -- pure streaming segmented sum
__global__ __launch_bounds__(256) void k_gatherH(const float4* __restrict__ X2Ws,
        const int* __restrict__ rowptrR, float4* __restrict__ hf) {
    int t = threadIdx.x;
    int g = blockIdx.x * 16 + (t >> 4);
    int f4 = t & 15;
    int st = rowptrR[g], en = rowptrR[g + 1];
    float4 acc = {0.f, 0.f, 0.f, 0.f};
    for (int p = st; p < en; p++) {
        float4 a = X2Ws[(size_t)p * 16 + f4];
        acc.x += a.x; acc.y += a.y; acc.z += a.z; acc.w += a.w;
    }
    hf[(size_t)g * 16 + f4] = acc;
}

// final GCN aggregate + bias + log_softmax; edge loop unrolled x4
__global__ __launch_bounds__(256) void k_final(const float4* __restrict__ hf,
        const float* __restrict__ dinvN, const int* __restrict__ rowptr,
        const int* __restrict__ col, const float* __restrict__ bfb,
        float4* __restrict__ out) {
    int t = threadIdx.x;
    int n = blockIdx.x * 16 + (t >> 4);
    int f4 = t & 15;
    int st = rowptr[n], en = rowptr[n + 1];
    float4 acc = {0.f, 0.f, 0.f, 0.f};
    int p = st;
    for (; p + 4 <= en; p += 4) {
        int s0 = col[p + 0], s1 = col[p + 1], s2 = col[p + 2], s3 = col[p + 3];
        float d0 = dinvN[s0], d1 = dinvN[s1], d2 = dinvN[s2], d3 = dinvN[s3];
        float4 h0 = hf[(size_t)s0 * 16 + f4];
        float4 h1 = hf[(size_t)s1 * 16 + f4];
        float4 h2 = hf[(size_t)s2 * 16 + f4];
        float4 h3 = hf[(size_t)s3 * 16 + f4];
        acc.x += h0.x * d0; acc.y += h0.y * d0; acc.z += h0.z * d0; acc.w += h0.w * d0;
        acc.x += h1.x * d1; acc.y += h1.y * d1; acc.z += h1.z * d1; acc.w += h1.w * d1;
        acc.x += h2.x * d2; acc.y += h2.y * d2; acc.z += h2.z * d2; acc.w += h2.w * d2;
        acc.x += h3.x * d3; acc.y += h3.y * d3; acc.z += h3.z * d3; acc.w += h3.w * d3;
    }
    for (; p < en; p++) {
        int src = col[p];
        float d = dinvN[src];
        float4 hv = hf[(size_t)src * 16 + f4];
        acc.x += hv.x * d; acc.y += hv.y * d; acc.z += hv.z * d; acc.w += hv.w * d;
    }
    float dn = dinvN[n];
    float dn2 = dn * dn;
    float4 hs = hf[(size_t)n * 16 + f4];
    float4 bb = ((const float4*)bfb)[f4];
    float4 x;
    x.x = acc.x * dn + hs.x * dn2 + bb.x;
    x.y = acc.y * dn + hs.y * dn2 + bb.y;
    x.z = acc.z * dn + hs.z * dn2 + bb.z;
    x.w = acc.w * dn + hs.w * dn2 + bb.w;
    float m = fmaxf(fmaxf(x.x, x.y), fmaxf(x.z, x.w));
    for (int o = 1; o < 16; o <<= 1) m = fmaxf(m, __shfl_xor(m, o, 64));
    float ssum = expf(x.x - m) + expf(x.y - m) + expf(x.z - m) + expf(x.w - m);
    for (int o = 1; o < 16; o <<= 1) ssum += __shfl_xor(ssum, o, 64);
    float lz = m + logf(ssum);
    float4 r = { x.x - lz, x.y - lz, x.z - lz, x.w - lz };
    out[(size_t)n * 16 + f4] = r;
}

// ---------------- host ----------------
extern "C" void kernel_launch(void* const* d_in, const int* in_sizes, int n_in,
                              void* d_out, int out_size, void* d_ws, size_t ws_size,
                              hipStream_t stream) {
    const float* sub_x = (const float*)d_in[0];
    const int*   sei   = (const int*)d_in[1];
    const int*   sorig = (const int*)d_in[2];
    const int*   gei   = (const int*)d_in[3];
    const float *W1 = (const float*)d_in[4],  *b1  = (const float*)d_in[5];
    const float *W2 = (const float*)d_in[6],  *b2  = (const float*)d_in[7];
    const float *Wp = (const float*)d_in[8],  *bp  = (const float*)d_in[9];
    const float *Wsc = (const float*)d_in[10], *bsc = (const float*)d_in[11];
    const float *Wqkv = (const float*)d_in[12], *bqkv = (const float*)d_in[13];
    const float *Wo = (const float*)d_in[14], *bo  = (const float*)d_in[15];
    const float *Wf = (const float*)d_in[16], *bfb = (const float*)d_in[17];

    float* out0 = (float*)d_out;                      // log-softmax [NG,64]
    float* gemb = (float*)d_out + (size_t)NG * 64;    // global_emb [NG,384] in-place

    char* w = (char*)d_ws;
    size_t off = 0;
    auto alloc = [&](size_t nbytes) -> void* {
        off = (off + 255) & ~(size_t)255;
        void* p = w + off;
        off += nbytes;
        return p;
    };
    // bcur + cntR adjacent -> single memset covers both
    int*   bcur    = (int*)alloc(64 * 4);              // counts (init 0)
    int*   cntR    = (int*)alloc((size_t)NG * 4);
    float* AW      = (float*)alloc((size_t)S * 64 * 4);
    float* dinv    = (float*)alloc((size_t)NG * 4);        // subgraph dinv; later dinvN
    float* scoreh  = (float*)alloc((size_t)NG * 4);
    float* score   = (float*)alloc((size_t)NG * 4);
    float* gate    = (float*)alloc((size_t)S * KSEL * 4);
    float* dinv2   = (float*)alloc((size_t)S * KSEL * 4);
    float* subemb  = (float*)alloc((size_t)S * 256 * 4);
    float* att     = (float*)alloc((size_t)S * 256 * 4);
    int*   perm    = (int*)alloc((size_t)S * KSEL * 4);
    int*   posmap  = (int*)alloc((size_t)NG * 4);
    int*   cur_sub = (int*)alloc((size_t)NG * 4);          // used as curR
    int*   rowptr_s= (int*)alloc((size_t)(NG + 64) * 4);   // alias: rowptrN
    int*   col_sub = (int*)alloc((size_t)EG * 4);          // alias: colN
    int*   rowptrR = (int*)alloc((size_t)(NG + 64) * 4);
    int*   rowlist = (int*)alloc((size_t)NG * 4);
    int*   posR    = (int*)alloc((size_t)NG * 4);
    float* x1      = (float*)alloc((size_t)NG * NH * 4);   // alias: xsub, later X2Ws
    float* x2s     = (float*)alloc((size_t)NG * NH * 4);   // GCN2 out, PERMUTED to rowlist order
    float* hbuf    = (float*)alloc((size_t)NG * NH * 4);   // alias: hf
    float* xpool   = (float*)alloc((size_t)S * KSEL * NH * 4);  // alias: ebin
    float* xsub    = x1;
    float* hf      = hbuf;
    float* dinvN   = dinv;
    float* X2Ws    = x1;                                   // x1 dead after k_ea_fb
    int*   curR    = cur_sub;
    int*   rowptrN = rowptr_s;
    int*   colN    = col_sub;
    int*   ebin    = (int*)xpool;                          // xpool dead after k_emb_mmP

    hipMemsetAsync(bcur, 0, 256 + (size_t)NG * 4, stream);   // bcur + cntR in one

    // csr_sub + countR || mm1 first half; scanR || mm1 second half; fillR
    k_csr_mm1<<<384, 1024, 0, stream>>>(sei, sorig, rowptr_s, col_sub, dinv, cntR,
                                        sub_x, W1, hbuf);
    k_scan_mm1<<<320, 1024, 0, stream>>>(cntR, rowptrR, curR, sub_x, W1, hbuf);
    k_fillR<<<NG / 256, 256, 0, stream>>>(sorig, curR, rowlist, posR);

    // GCN1 aggregate (+ fused scorer h = x1 @ Wp)
    k_agg1<<<8192, 256, 0, stream>>>((const float4*)hbuf, dinv, rowptr_s, col_sub,
                                     b1, Wp, (float4*)x1, scoreh);
    // score_agg (first) || GCN2 matmul
    k_mm2s<<<256 + 2048, 256, 0, stream>>>(x1, W2, hbuf,
                                           scoreh, dinv, rowptr_s, col_sub, bp, score);
    // top-K (first) || GCN2 aggregate (rowlist-order scatter)
    k_topk_agg2<<<64 + 4096, 512, 0, stream>>>((const float4*)hbuf, dinv, rowptr_s, col_sub,
                                               b2, posR, (float4*)x2s,
                                               score, perm, gate, posmap);
    // pooling
    k_pool<<<(S * KSEL) / 8, 256, 0, stream>>>((const float4*)x1, perm, gate, posmap,
                                               rowptr_s, col_sub, dinv2, (float4*)xpool);
    // emb pass 1 || mmP (xpool @ Wsc)
    k_emb_mmP<<<64 + (S * KSEL) / 128, 1024, 0, stream>>>(xpool, subemb, Wsc, hbuf);
    // binN (first) || pooled aggregate
    k_aggp_bin<<<128 + 4096, 256, 0, stream>>>((const float4*)hbuf, dinv2, perm, posmap,
                                               rowptr_s, col_sub, bsc, (float4*)xsub,
                                               gei, bcur, ebin);
    // emb pass2 + attention + AW || fillB3 (128 blocks -> all resident)
    k_ea_fb<<<128, 1024, 0, stream>>>(xsub, subemb, Wqkv, bqkv, Wo, bo, Wf, att, AW,
                                      ebin, bcur, rowptrN, dinvN, colN);
    // X2Ws matmul (first) || streaming gather of gemb
    k_gx<<<NG / 64 + NG / 8, 256, 0, stream>>>((const float4*)x2s, (const float4*)att,
                                               rowptrR, rowlist, (float4*)gemb,
                                               x2s, Wf, AW, X2Ws);
    k_gatherH<<<NG / 16, 256, 0, stream>>>((const float4*)X2Ws, rowptrR, (float4*)hf);

    // final GCN + log_softmax
    k_final<<<NG / 16, 256, 0, stream>>>((const float4*)hf, dinvN, rowptrN, colN, bfb, (float4*)out0);

    (void)in_sizes; (void)n_in; (void)out_size; (void)ws_size;
}